// Round 3
// baseline (3044.825 us; speedup 1.0000x reference)
//
#include <hip/hip_runtime.h>
#include <cstdint>
#include <cstddef>

// Problem constants
#define NB 256
#define SQ 500
#define NROWS (NB * SQ)   // 128000
#define DQ 128
#define DV 256
#define MM 50
#define FF 512
#define WSTRIDE 52        // padded w-row stride (16B aligned: 52*4=208)
#define MVSTATE_FLOATS (NB * MM * DV)   // 3,276,800

__device__ __forceinline__ float4 ld4(const float* p) {
    return *reinterpret_cast<const float4*>(p);
}
__device__ __forceinline__ float sigf(float x) { return 1.f / (1.f + __expf(-x)); }
__device__ __forceinline__ float tanhfast(float x) { return 2.f / (1.f + __expf(-2.f * x)) - 1.f; }
// local chunk row -> global row:  n = (l/CS)*SQ + s0 + (l%CS)
__device__ __forceinline__ int gmap(int l, int s0, int CS) {
    int b = (unsigned)l / (unsigned)CS;
    return b * SQ + s0 + (l - b * CS);
}

// ---------------------------------------------------------------------------
// prep: X1 = te+qe ; S3 = he+hte+ae ; X2 = S3+qe ; QE = qe   (chunk [Nc,128])
// ---------------------------------------------------------------------------
__global__ __launch_bounds__(256) void prep128(
    const int* __restrict__ q_data, const int* __restrict__ time_data,
    const int* __restrict__ attempt_data, const int* __restrict__ hint_data,
    const int* __restrict__ hintT_data,
    const float* __restrict__ q_emb, const float* __restrict__ time_emb,
    const float* __restrict__ attempt_emb, const float* __restrict__ ht_emb,
    float* __restrict__ X1, float* __restrict__ X2, float* __restrict__ S3,
    float* __restrict__ QE, int s0, int CS, int Nc)
{
    int g = blockIdx.x * 256 + threadIdx.x;
    int l = g >> 5;
    int kq = (g & 31) << 2;
    if (l >= Nc) return;
    int n = gmap(l, s0, CS);
    float4 qe  = ld4(q_emb       + (size_t)q_data[n]       * DQ + kq);
    float4 te  = ld4(time_emb    + (size_t)time_data[n]    * DQ + kq);
    float4 ae  = ld4(attempt_emb + (size_t)attempt_data[n] * DQ + kq);
    float4 he  = ld4(ht_emb      + (size_t)hint_data[n]    * DQ + kq);
    float4 hte = ld4(ht_emb      + (size_t)hintT_data[n]   * DQ + kq);
    size_t off = (size_t)l * DQ + kq;
    float4 x1, s3, x2;
    x1.x = te.x + qe.x; x1.y = te.y + qe.y; x1.z = te.z + qe.z; x1.w = te.w + qe.w;
    s3.x = he.x + hte.x + ae.x; s3.y = he.y + hte.y + ae.y;
    s3.z = he.z + hte.z + ae.z; s3.w = he.w + hte.w + ae.w;
    x2.x = s3.x + qe.x; x2.y = s3.y + qe.y; x2.z = s3.z + qe.z; x2.w = s3.w + qe.w;
    *(float4*)(X1 + off) = x1;
    *(float4*)(X2 + off) = x2;
    *(float4*)(S3 + off) = s3;
    *(float4*)(QE + off) = qe;
}

// ---------------------------------------------------------------------------
// input_embed = q_proc + time_final * te   (te re-gathered)
// ---------------------------------------------------------------------------
__global__ __launch_bounds__(256) void ew_ie(
    const float* __restrict__ QP, const float* __restrict__ TF,
    const int* __restrict__ time_data, const float* __restrict__ time_emb,
    float* __restrict__ IE, int s0, int CS, int Nc)
{
    int g = blockIdx.x * 256 + threadIdx.x;
    int l = g >> 5;
    int kq = (g & 31) << 2;
    if (l >= Nc) return;
    int n = gmap(l, s0, CS);
    size_t off = (size_t)l * DQ + kq;
    float4 te = ld4(time_emb + (size_t)time_data[n] * DQ + kq);
    float4 qp = ld4(QP + off);
    float4 tf = ld4(TF + off);
    float4 o;
    o.x = fmaf(tf.x, te.x, qp.x); o.y = fmaf(tf.y, te.y, qp.y);
    o.z = fmaf(tf.z, te.z, qp.z); o.w = fmaf(tf.w, te.w, qp.w);
    *(float4*)(IE + off) = o;
}

// ---------------------------------------------------------------------------
// Generic fp32 GEMM: Y = epilogue(act(X @ W^T + bias))
// BM=BN=128, BK=32, 256 threads, 8x8 register tile.
// GATHER: A-rows from gtab[gidx[gmap(row)]]. CONCAT: A = [X(256) | Xb(128)].
// ---------------------------------------------------------------------------
enum { ACT_NONE = 0, ACT_TANH = 1, ACT_SIG = 2 };
enum { EPI_STORE = 0, EPI_X3 = 1, EPI_PRED = 2 };

template <int ACT, int EPI, bool GATHER, bool CONCAT>
__global__ __launch_bounds__(256) void gemm_k(
    const float* X, const int* __restrict__ gidx, const float* __restrict__ gtab,
    const float* __restrict__ Xb,
    const float* __restrict__ W, const float* __restrict__ bias,
    float* Y, const float* E1, const float* E2,
    const float* __restrict__ predW, int K, int C, int s0, int CS)
{
    __shared__ float As[32][132];   // transposed: As[k][row]
    __shared__ float Ws[32][132];   // Ws[k][col]
    const int tid = threadIdx.x;
    const int row0 = blockIdx.x * 128;
    const int col0 = blockIdx.y * 128;
    const int tx = tid & 15;
    const int ty = tid >> 4;

    float acc[8][8];
#pragma unroll
    for (int i = 0; i < 8; ++i)
#pragma unroll
        for (int j = 0; j < 8; ++j) acc[i][j] = 0.f;

    for (int kt = 0; kt < K; kt += 32) {
#pragma unroll
        for (int i = 0; i < 4; ++i) {
            const int f = tid + i * 256;      // [0,1024)
            const int r = f >> 3;             // row/col within tile [0,128)
            const int kq = (f & 7) << 2;      // k within tile {0,4,...,28}
            const int kg = kt + kq;
            const float* src;
            if constexpr (CONCAT) {
                src = (kg < 256) ? (X + (size_t)(row0 + r) * 256 + kg)
                                 : (Xb + (size_t)(row0 + r) * 128 + (kg - 256));
            } else if constexpr (GATHER) {
                src = gtab + (size_t)gidx[gmap(row0 + r, s0, CS)] * K + kg;
            } else {
                src = X + (size_t)(row0 + r) * K + kg;
            }
            float4 av = ld4(src);
            As[kq + 0][r] = av.x; As[kq + 1][r] = av.y;
            As[kq + 2][r] = av.z; As[kq + 3][r] = av.w;
            float4 wv = ld4(W + (size_t)(col0 + r) * K + kg);
            Ws[kq + 0][r] = wv.x; Ws[kq + 1][r] = wv.y;
            Ws[kq + 2][r] = wv.z; Ws[kq + 3][r] = wv.w;
        }
        __syncthreads();
#pragma unroll
        for (int k = 0; k < 32; ++k) {
            float a[8], bv[8];
            *(float4*)&a[0]  = ld4(&As[k][ty * 4]);
            *(float4*)&a[4]  = ld4(&As[k][64 + ty * 4]);
            *(float4*)&bv[0] = ld4(&Ws[k][tx * 4]);
            *(float4*)&bv[4] = ld4(&Ws[k][64 + tx * 4]);
#pragma unroll
            for (int i = 0; i < 8; ++i)
#pragma unroll
                for (int j = 0; j < 8; ++j)
                    acc[i][j] = fmaf(a[i], bv[j], acc[i][j]);
        }
        __syncthreads();
    }

    int rloc[8], cloc[8];
#pragma unroll
    for (int i = 0; i < 4; ++i) {
        rloc[i] = ty * 4 + i; rloc[4 + i] = 64 + ty * 4 + i;
        cloc[i] = tx * 4 + i; cloc[4 + i] = 64 + tx * 4 + i;
    }
    float bvals[8];
#pragma unroll
    for (int j = 0; j < 8; ++j) bvals[j] = bias[col0 + cloc[j]];

    if constexpr (EPI == EPI_PRED) {
        // rc = tanh(acc+bias); partial = sum_c rc*predW[c]; LDS-reduce; atomic per row
        float pw[8];
#pragma unroll
        for (int j = 0; j < 8; ++j) pw[j] = predW[col0 + cloc[j]];
        float* red = &As[0][0];   // reuse: 128*17 floats < 32*132
#pragma unroll
        for (int i = 0; i < 8; ++i) {
            float pp = 0.f;
#pragma unroll
            for (int j = 0; j < 8; ++j) {
                float v = tanhfast(acc[i][j] + bvals[j]);
                pp = fmaf(v, pw[j], pp);
            }
            red[rloc[i] * 17 + tx] = pp;
        }
        __syncthreads();
        if (tid < 128) {
            float s = 0.f;
#pragma unroll
            for (int t = 0; t < 16; ++t) s += red[tid * 17 + t];
            atomicAdd(&Y[row0 + tid], s);
        }
    } else {
#pragma unroll
        for (int i = 0; i < 8; ++i) {
            const int r = row0 + rloc[i];
#pragma unroll
            for (int jh = 0; jh < 2; ++jh) {
                float tmp[4];
#pragma unroll
                for (int jj = 0; jj < 4; ++jj) {
                    const int j = jh * 4 + jj;
                    float x = acc[i][j] + bvals[j];
                    if constexpr (ACT == ACT_TANH) x = tanhfast(x);
                    else if constexpr (ACT == ACT_SIG) x = sigf(x);
                    tmp[jj] = x;
                }
                const int cbase = (jh ? 64 : 0) + tx * 4;
                float4 v;
                if constexpr (EPI == EPI_X3) {
                    // X3 = QE + sigmoid(...)*S3  (C==128, col0==0, in-place safe)
                    size_t off = (size_t)r * 128 + cbase;
                    float4 qe = ld4(E1 + off);
                    float4 s3 = ld4(E2 + off);
                    v.x = fmaf(tmp[0], s3.x, qe.x);
                    v.y = fmaf(tmp[1], s3.y, qe.y);
                    v.z = fmaf(tmp[2], s3.z, qe.z);
                    v.w = fmaf(tmp[3], s3.w, qe.w);
                    *(float4*)(Y + off) = v;
                } else {
                    v.x = tmp[0]; v.y = tmp[1]; v.z = tmp[2]; v.w = tmp[3];
                    *(float4*)(Y + (size_t)r * C + col0 + cbase) = v;
                }
            }
        }
    }
}

// ---------------------------------------------------------------------------
// w = softmax(q_proc @ Mk^T): one wave per row; lane m (<50) does the 128-dot
// ---------------------------------------------------------------------------
__global__ __launch_bounds__(256) void wsoftmax(
    const float* __restrict__ QP, const float* __restrict__ Mk,
    float* __restrict__ Wb, int Nc)
{
    int gw = (blockIdx.x * 256 + threadIdx.x) >> 6;
    int lane = threadIdx.x & 63;
    if (gw >= Nc) return;
    const float* q = QP + (size_t)gw * DQ;
    float logit = -3.0e38f;
    if (lane < MM) {
        const float* mk = Mk + lane * DQ;
        float s0 = 0.f, s1 = 0.f, s2 = 0.f, s3 = 0.f;
#pragma unroll
        for (int k = 0; k < DQ; k += 4) {
            float4 qv = ld4(q + k);
            float4 mv = ld4(mk + k);
            s0 = fmaf(qv.x, mv.x, s0); s1 = fmaf(qv.y, mv.y, s1);
            s2 = fmaf(qv.z, mv.z, s2); s3 = fmaf(qv.w, mv.w, s3);
        }
        logit = (s0 + s1) + (s2 + s3);
    }
    float mx = logit;
#pragma unroll
    for (int off = 32; off; off >>= 1) mx = fmaxf(mx, __shfl_xor(mx, off));
    float ex = (lane < MM) ? __expf(logit - mx) : 0.f;
    float sum = ex;
#pragma unroll
    for (int off = 32; off; off >>= 1) sum += __shfl_xor(sum, off);
    if (lane < MM) Wb[(size_t)gw * WSTRIDE + lane] = ex / sum;
}

// ---------------------------------------------------------------------------
// DKVMN scan over one S-chunk: 256 blocks (batch b) x 256 threads (dim d).
// Mv column in 50 registers/thread; ping-pong prefetch of (w,e,a).
// first!=0: load Mv from Mv0 broadcast; else from MvSt. Always store back.
// ---------------------------------------------------------------------------
__device__ __forceinline__ void load_w(float* w, const float* __restrict__ src) {
#pragma unroll
    for (int i = 0; i < 13; ++i) {
        float4 v = ld4(src + i * 4);
        w[i * 4 + 0] = v.x; w[i * 4 + 1] = v.y;
        w[i * 4 + 2] = v.z; w[i * 4 + 3] = v.w;
    }
}

__global__ __launch_bounds__(256) void scan_kernel(
    const float* __restrict__ Wb, const float* __restrict__ EE,
    const float* __restrict__ AA, const float* __restrict__ Mv0,
    float* __restrict__ MvSt, float* __restrict__ RD, int CS, int first)
{
    const int b = blockIdx.x;
    const int d = threadIdx.x;
    float mv[MM];
    if (first) {
#pragma unroll
        for (int m = 0; m < MM; ++m) mv[m] = Mv0[m * DV + d];
    } else {
#pragma unroll
        for (int m = 0; m < MM; ++m) mv[m] = MvSt[((size_t)b * MM + m) * DV + d];
    }

    const float* wrow = Wb + (size_t)b * CS * WSTRIDE;
    const float* ep = EE + (size_t)b * CS * DV + d;
    const float* ap = AA + (size_t)b * CS * DV + d;
    float* rp = RD + (size_t)b * CS * DV + d;

    float wA[52], wB[52];
    float eA, aA, eB, aB;
    load_w(wA, wrow); eA = *ep; aA = *ap;

    for (int t = 0; t < CS; t += 2) {   // CS is even by construction
        // prefetch step t+1
        load_w(wB, wrow + WSTRIDE); eB = ep[DV]; aB = ap[DV];

        // ---- step t (wA) ----
        {
            float r0 = 0.f, r1 = 0.f, r2 = 0.f, r3 = 0.f;
#pragma unroll
            for (int m = 0; m < 48; m += 4) {
                r0 = fmaf(wA[m + 0], mv[m + 0], r0);
                r1 = fmaf(wA[m + 1], mv[m + 1], r1);
                r2 = fmaf(wA[m + 2], mv[m + 2], r2);
                r3 = fmaf(wA[m + 3], mv[m + 3], r3);
            }
            r0 = fmaf(wA[48], mv[48], r0);
            r1 = fmaf(wA[49], mv[49], r1);
            *rp = (r0 + r2) + (r1 + r3);
#pragma unroll
            for (int m = 0; m < MM; ++m) {
                float wm = wA[m];
                mv[m] = fmaf(mv[m], fmaf(-wm, eA, 1.f), wm * aA);
            }
        }
        wrow += 2 * WSTRIDE; ep += 2 * DV; ap += 2 * DV;

        // prefetch step t+2 (uniform branch; guards OOB at the tail)
        if (t + 2 < CS) { load_w(wA, wrow); eA = *ep; aA = *ap; }

        // ---- step t+1 (wB) ----
        {
            float r0 = 0.f, r1 = 0.f, r2 = 0.f, r3 = 0.f;
#pragma unroll
            for (int m = 0; m < 48; m += 4) {
                r0 = fmaf(wB[m + 0], mv[m + 0], r0);
                r1 = fmaf(wB[m + 1], mv[m + 1], r1);
                r2 = fmaf(wB[m + 2], mv[m + 2], r2);
                r3 = fmaf(wB[m + 3], mv[m + 3], r3);
            }
            r0 = fmaf(wB[48], mv[48], r0);
            r1 = fmaf(wB[49], mv[49], r1);
            rp[DV] = (r0 + r2) + (r1 + r3);
#pragma unroll
            for (int m = 0; m < MM; ++m) {
                float wm = wB[m];
                mv[m] = fmaf(mv[m], fmaf(-wm, eB, 1.f), wm * aB);
            }
        }
        rp += 2 * DV;
    }
#pragma unroll
    for (int m = 0; m < MM; ++m) MvSt[((size_t)b * MM + m) * DV + d] = mv[m];
}

// ---------------------------------------------------------------------------
// loss + outputs (per chunk; le/mf accumulate into R2)
// ---------------------------------------------------------------------------
__global__ __launch_bounds__(256) void loss_part(
    const float* __restrict__ P, const int* __restrict__ target,
    const float* __restrict__ pred_b, float* __restrict__ out,
    float* __restrict__ R2, int s0, int CS, int Nc)
{
    int l = blockIdx.x * 256 + threadIdx.x;
    float le = 0.f, mf = 0.f;
    if (l < Nc) {
        int n = gmap(l, s0, CS);
        float p = P[l] + pred_b[0];
        int t = target[n];
        float y = (t >= 1) ? (float)(t - 1) : 0.f;
        float sig = 1.f / (1.f + __expf(-p));
        if (t >= 1) {
            mf = 1.f;
            le = fmaxf(p, 0.f) + log1pf(__expf(-fabsf(p))) - p * y;
        }
        out[1 + n] = sig * mf;
        out[1 + NROWS + n] = y * mf;
    }
#pragma unroll
    for (int off = 32; off; off >>= 1) {
        le += __shfl_down(le, off);
        mf += __shfl_down(mf, off);
    }
    __shared__ float sl[4], sm[4];
    int wid = threadIdx.x >> 6;
    if ((threadIdx.x & 63) == 0) { sl[wid] = le; sm[wid] = mf; }
    __syncthreads();
    if (threadIdx.x == 0) {
        atomicAdd(R2, sl[0] + sl[1] + sl[2] + sl[3]);
        atomicAdd(R2 + 1, sm[0] + sm[1] + sm[2] + sm[3]);
    }
}

__global__ void loss_fin(const float* __restrict__ R2, float* __restrict__ out)
{
    out[0] = R2[0] / fmaxf(R2[1], 1.f);
}

// ---------------------------------------------------------------------------
extern "C" void kernel_launch(void* const* d_in, const int* in_sizes, int n_in,
                              void* d_out, int out_size, void* d_ws, size_t ws_size,
                              hipStream_t stream)
{
    const int* q_data       = (const int*)d_in[0];
    const int* qa_data      = (const int*)d_in[1];
    const int* target       = (const int*)d_in[2];
    const int* time_data    = (const int*)d_in[3];
    const int* attempt_data = (const int*)d_in[4];
    const int* hint_data    = (const int*)d_in[5];
    const int* hintT_data   = (const int*)d_in[6];
    const float* q_emb    = (const float*)d_in[7];
    const float* qa_emb   = (const float*)d_in[8];
    const float* time_emb = (const float*)d_in[9];
    const float* att_emb  = (const float*)d_in[10];
    const float* ht_emb   = (const float*)d_in[11];
    const float* Mk       = (const float*)d_in[12];
    const float* Mv0      = (const float*)d_in[13];
    const float* diff_W   = (const float*)d_in[14];
    const float* diff_b   = (const float*)d_in[15];
    const float* diff2_W  = (const float*)d_in[16];
    const float* diff2_b  = (const float*)d_in[17];
    const float* erase_W  = (const float*)d_in[18];
    const float* erase_b  = (const float*)d_in[19];
    const float* add_W    = (const float*)d_in[20];
    const float* add_b    = (const float*)d_in[21];
    const float* read_W   = (const float*)d_in[22];
    const float* read_b   = (const float*)d_in[23];
    const float* pred_W   = (const float*)d_in[24];
    const float* pred_b   = (const float*)d_in[25];
    float* out = (float*)d_out;
    (void)in_sizes; (void)n_in; (void)out_size;

    // Pick largest EVEN divisor of 500 whose chunk workspace fits ws_size.
    // Per-chunk floats: Nc*1025 (buf0..buf3=4*128, AA+RD=2*256, bufP=1; EE
    // aliases buf0+buf1) + MvState + R2.
    static const int cs_opts[] = {500, 250, 100, 50, 20, 10, 4, 2};
    int CS = 0;
    for (int i = 0; i < 8; ++i) {
        size_t need = ((size_t)NB * cs_opts[i] * 1025 + MVSTATE_FLOATS + 2) * sizeof(float);
        if (need <= ws_size) { CS = cs_opts[i]; break; }
    }
    if (CS == 0) return;   // workspace hopeless; stay alive for a readable failure
    const int NCH = SQ / CS;
    const int Nc = NB * CS;

    float* ws    = (float*)d_ws;
    float* buf0  = ws;                           // X1/T1/time_final  [Nc,128]
    float* buf1  = buf0 + (size_t)Nc * 128;      // QE/X3/q_proc      [Nc,128]
    float* bufEE = buf0;                         // erase gate        [Nc,256] (alias)
    float* buf2  = buf1 + (size_t)Nc * 128;      // X2/T2/input_embed [Nc,128]
    float* buf3  = buf2 + (size_t)Nc * 128;      // S3 -> w (stride52)[Nc,128]
    float* bufAA = buf3 + (size_t)Nc * 128;      // add vec           [Nc,256]
    float* bufRD = bufAA + (size_t)Nc * 256;     // reads             [Nc,256]
    float* bufP  = bufRD + (size_t)Nc * 256;     // pred partials     [Nc]
    float* MvSt  = bufP + Nc;                    // Mv carry state    [NB,MM,DV]
    float* bufR2 = MvSt + MVSTATE_FLOATS;        // loss partials     [2]

    hipMemsetAsync(bufR2, 0, 2 * sizeof(float), stream);

    for (int c = 0; c < NCH; ++c) {
        const int s0 = c * CS;

        prep128<<<Nc / 8, 256, 0, stream>>>(
            q_data, time_data, attempt_data, hint_data, hintT_data,
            q_emb, time_emb, att_emb, ht_emb, buf0, buf2, buf3, buf1, s0, CS, Nc);

        dim3 g128(Nc / 128, 1);
        // T1 = tanh(lin1(te+qe))          (in-place buf0)
        gemm_k<ACT_TANH, EPI_STORE, false, false><<<g128, 256, 0, stream>>>(
            buf0, nullptr, nullptr, nullptr, diff_W, diff_b, buf0, nullptr, nullptr, nullptr, 128, 128, s0, CS);
        // T2 = tanh(lin1(hte+he+ae+qe))   (in-place buf2)
        gemm_k<ACT_TANH, EPI_STORE, false, false><<<g128, 256, 0, stream>>>(
            buf2, nullptr, nullptr, nullptr, diff_W, diff_b, buf2, nullptr, nullptr, nullptr, 128, 128, s0, CS);
        // time_final = sigmoid(lin2(T1))  (in-place buf0)
        gemm_k<ACT_SIG, EPI_STORE, false, false><<<g128, 256, 0, stream>>>(
            buf0, nullptr, nullptr, nullptr, diff2_W, diff2_b, buf0, nullptr, nullptr, nullptr, 128, 128, s0, CS);
        // diff_final = sigmoid(lin2(T2)); fused X3 = QE + df*S3 -> buf1
        gemm_k<ACT_SIG, EPI_X3, false, false><<<g128, 256, 0, stream>>>(
            buf2, nullptr, nullptr, nullptr, diff2_W, diff2_b, buf1, buf1, buf3, nullptr, 128, 128, s0, CS);
        // q_proc = lin1(X3)               (in-place buf1)
        gemm_k<ACT_NONE, EPI_STORE, false, false><<<g128, 256, 0, stream>>>(
            buf1, nullptr, nullptr, nullptr, diff_W, diff_b, buf1, nullptr, nullptr, nullptr, 128, 128, s0, CS);

        // input_embed = q_proc + time_final * te  -> buf2
        ew_ie<<<Nc / 8, 256, 0, stream>>>(buf1, buf0, time_data, time_emb, buf2, s0, CS, Nc);

        // w = softmax(q_proc @ Mk^T) -> buf3 (stride 52)
        wsoftmax<<<Nc / 4, 256, 0, stream>>>(buf1, Mk, buf3, Nc);

        dim3 g256(Nc / 128, 2);
        // E = sigmoid(qa_e @ erase_W^T + b), gather fused  (buf0/buf1 now dead)
        gemm_k<ACT_SIG, EPI_STORE, true, false><<<g256, 256, 0, stream>>>(
            nullptr, qa_data, qa_emb, nullptr, erase_W, erase_b, bufEE, nullptr, nullptr, nullptr, 256, 256, s0, CS);
        // A = tanh(qa_e @ add_W^T + b), gather fused
        gemm_k<ACT_TANH, EPI_STORE, true, false><<<g256, 256, 0, stream>>>(
            nullptr, qa_data, qa_emb, nullptr, add_W, add_b, bufAA, nullptr, nullptr, nullptr, 256, 256, s0, CS);

        // sequential DKVMN scan over this chunk -> reads; carries MvSt
        scan_kernel<<<NB, DV, 0, stream>>>(buf3, bufEE, bufAA, Mv0, MvSt, bufRD, CS, c == 0 ? 1 : 0);

        hipMemsetAsync(bufP, 0, (size_t)Nc * sizeof(float), stream);

        // rc = tanh([reads|input_embed] @ read_W^T + read_b); pred -> bufP
        dim3 gf(Nc / 128, 4);
        gemm_k<ACT_TANH, EPI_PRED, false, true><<<gf, 256, 0, stream>>>(
            bufRD, nullptr, nullptr, buf2, read_W, read_b, bufP, nullptr, nullptr, pred_W, 384, 512, s0, CS);

        loss_part<<<Nc / 256, 256, 0, stream>>>(bufP, target, pred_b, out, bufR2, s0, CS, Nc);
    }

    loss_fin<<<1, 1, 0, stream>>>(bufR2, out);
}

// Round 4
// 1526.690 us; speedup vs baseline: 1.9944x; 1.9944x over previous
//
#include <hip/hip_runtime.h>
#include <cstdint>
#include <cstddef>

// Problem constants
#define NB 256
#define SQ 500
#define NROWS (NB * SQ)   // 128000
#define DQ 128
#define DV 256
#define MM 50
#define FF 512
#define WSTRIDE 52        // padded w-row stride (16B aligned)

typedef _Float16 half8 __attribute__((ext_vector_type(8)));
typedef float floatx4 __attribute__((ext_vector_type(4)));
typedef unsigned short u16;
typedef unsigned int u32;

__device__ __forceinline__ float4 ld4(const float* p) {
    return *reinterpret_cast<const float4*>(p);
}
__device__ __forceinline__ float sigf(float x) { return 1.f / (1.f + __expf(-x)); }
__device__ __forceinline__ float tanhfast(float x) { return 2.f / (1.f + __expf(-2.f * x)) - 1.f; }
__device__ __forceinline__ int gmap(int l, int s0, int CS) {
    int b = (unsigned)l / (unsigned)CS;
    return b * SQ + s0 + (l - b * CS);
}
__device__ __forceinline__ void st4h(u16* dst, float4 v) {
    _Float16 h0 = (_Float16)v.x, h1 = (_Float16)v.y, h2 = (_Float16)v.z, h3 = (_Float16)v.w;
    ushort4 u;
    u.x = *(u16*)&h0; u.y = *(u16*)&h1; u.z = *(u16*)&h2; u.w = *(u16*)&h3;
    *(ushort4*)dst = u;
}
__device__ __forceinline__ float h2f(u16 b) { _Float16 h; *(u16*)&h = b; return (float)h; }
__device__ __forceinline__ u16 f2h(float x) { _Float16 h = (_Float16)x; return *(u16*)&h; }

// ---------------------------------------------------------------------------
// fp32 -> fp16 conversion (vec4)
// ---------------------------------------------------------------------------
__global__ __launch_bounds__(256) void cvt16(
    const float* __restrict__ s, u16* __restrict__ d, int n4)
{
    int i = blockIdx.x * 256 + threadIdx.x;
    if (i < n4) st4h(d + 4 * (size_t)i, ld4(s + 4 * (size_t)i));
}

// ---------------------------------------------------------------------------
// prep: Xp rows [0,Nc) = fp16(te+qe); rows [Nc,2Nc) = fp16(he+hte+ae+qe);
//       S3p = fp16(he+hte+ae); QEp = fp16(qe)
// ---------------------------------------------------------------------------
__global__ __launch_bounds__(256) void prep128(
    const int* __restrict__ q_data, const int* __restrict__ time_data,
    const int* __restrict__ attempt_data, const int* __restrict__ hint_data,
    const int* __restrict__ hintT_data,
    const float* __restrict__ q_emb, const float* __restrict__ time_emb,
    const float* __restrict__ attempt_emb, const float* __restrict__ ht_emb,
    u16* __restrict__ Xp, u16* __restrict__ S3p, u16* __restrict__ QEp,
    int s0, int CS, int Nc)
{
    int g = blockIdx.x * 256 + threadIdx.x;
    int l = g >> 5;
    int kq = (g & 31) << 2;
    if (l >= Nc) return;
    int n = gmap(l, s0, CS);
    float4 qe  = ld4(q_emb       + (size_t)q_data[n]       * DQ + kq);
    float4 te  = ld4(time_emb    + (size_t)time_data[n]    * DQ + kq);
    float4 ae  = ld4(attempt_emb + (size_t)attempt_data[n] * DQ + kq);
    float4 he  = ld4(ht_emb      + (size_t)hint_data[n]    * DQ + kq);
    float4 hte = ld4(ht_emb      + (size_t)hintT_data[n]   * DQ + kq);
    size_t off = (size_t)l * DQ + kq;
    float4 x1, s3, x2;
    x1.x = te.x + qe.x; x1.y = te.y + qe.y; x1.z = te.z + qe.z; x1.w = te.w + qe.w;
    s3.x = he.x + hte.x + ae.x; s3.y = he.y + hte.y + ae.y;
    s3.z = he.z + hte.z + ae.z; s3.w = he.w + hte.w + ae.w;
    x2.x = s3.x + qe.x; x2.y = s3.y + qe.y; x2.z = s3.z + qe.z; x2.w = s3.w + qe.w;
    st4h(Xp + off, x1);
    st4h(Xp + (size_t)Nc * DQ + off, x2);
    st4h(S3p + off, s3);
    st4h(QEp + off, qe);
}

// ---------------------------------------------------------------------------
// fp16 MFMA GEMM: Y = epi(act(A @ W^T + bias)), BM=BN=128, BK=32, 4 waves,
// wave tile 64x64 = 4x4 of v_mfma_f32_16x16x32_f16.
// MODE 1: tanh -> fp16 Yh (stride 128)               [lin1 on 2Nc rows]
// MODE 2: sig; row<Nc: tf->Yh; row>=Nc: x3=qe+v*s3 -> Yh  [lin2 batched]
// MODE 3: none; qp->Yh; fused ie=qp+tf*te -> AUX[,256:384] [lin1(X3)+ew_ie]
// MODE 4: gather A=qaE[idx]; by<2: sig->e, else tanh->a; packed u16 pairs->AUX
// MODE 5: tanh(rc); pred-partial reduce -> atomicAdd Yf    [readout+pred]
// ---------------------------------------------------------------------------
template <int MODE>
__global__ __launch_bounds__(256, 3) void gemm16(
    const u16* __restrict__ A, const u16* __restrict__ W0,
    const u16* __restrict__ W1, const float* __restrict__ b0,
    const float* __restrict__ b1, u16* __restrict__ Yh,
    float* __restrict__ Yf,
    const u16* __restrict__ QEp, const u16* __restrict__ S3p,
    const int* __restrict__ idx, const float* __restrict__ gtab,
    u16* __restrict__ AUX, const float* __restrict__ predW,
    int K, int Nc, int s0, int CS)
{
    __shared__ u16 smem[2 * 128 * 40];   // 20480 B: A-tile | B-tile (pitch 80B)
    u16* At = smem;
    u16* Bt = smem + 128 * 40;
    const int tid = threadIdx.x;
    const int row0 = blockIdx.x * 128;
    const int by = blockIdx.y;

    const u16* Wp;
    int col0;
    if constexpr (MODE == 4) { Wp = (by < 2) ? W0 : W1; col0 = (by & 1) * 128; }
    else { Wp = W0; col0 = by * 128; }
    const float* bias = (MODE == 4 && by >= 2) ? b1 : b0;

    floatx4 acc[4][4];
#pragma unroll
    for (int m = 0; m < 4; ++m)
#pragma unroll
        for (int n = 0; n < 4; ++n) acc[m][n] = (floatx4)0.f;

    const int lane = tid & 63, wv = tid >> 6;
    const int wr = (wv >> 1) * 64, wc = (wv & 1) * 64;
    const int q = lane >> 4, c0 = lane & 15;

    for (int kt = 0; kt < K; kt += 32) {
#pragma unroll
        for (int i = 0; i < 4; ++i) {
            int c = tid + i * 256;          // [0,1024)
            if (c < 512) {
                int r = c >> 2, seg = c & 3;
                const u16* src;
                if constexpr (MODE == 4) {
                    int g = idx[gmap(row0 + r, s0, CS)];
                    src = A + (size_t)g * K + kt + seg * 8;
                } else {
                    src = A + (size_t)(row0 + r) * K + kt + seg * 8;
                }
                *(uint4*)&At[r * 40 + seg * 8] = *(const uint4*)src;
            } else {
                int cb = c - 512;
                int r = cb >> 2, seg = cb & 3;
                const u16* src = Wp + (size_t)(col0 + r) * K + kt + seg * 8;
                *(uint4*)&Bt[r * 40 + seg * 8] = *(const uint4*)src;
            }
        }
        __syncthreads();
        half8 af[4], bf[4];
#pragma unroll
        for (int m = 0; m < 4; ++m) af[m] = *(half8*)&At[(wr + m * 16 + c0) * 40 + q * 8];
#pragma unroll
        for (int n = 0; n < 4; ++n) bf[n] = *(half8*)&Bt[(wc + n * 16 + c0) * 40 + q * 8];
#pragma unroll
        for (int m = 0; m < 4; ++m)
#pragma unroll
            for (int n = 0; n < 4; ++n)
                acc[m][n] = __builtin_amdgcn_mfma_f32_16x16x32_f16(af[m], bf[n], acc[m][n], 0, 0, 0);
        __syncthreads();
    }

    float bv[4];
#pragma unroll
    for (int n = 0; n < 4; ++n) bv[n] = bias[col0 + wc + n * 16 + c0];

    if constexpr (MODE == 5) {
        float pw[4];
#pragma unroll
        for (int n = 0; n < 4; ++n) pw[n] = predW[col0 + wc + n * 16 + c0];
        float* red = (float*)smem;          // [128][33] = 16896 B <= 20480
#pragma unroll
        for (int m = 0; m < 4; ++m)
#pragma unroll
            for (int r4 = 0; r4 < 4; ++r4) {
                int row = wr + m * 16 + q * 4 + r4;
                float pp = 0.f;
#pragma unroll
                for (int n = 0; n < 4; ++n)
                    pp = fmaf(tanhfast(acc[m][n][r4] + bv[n]), pw[n], pp);
                red[row * 33 + (wv & 1) * 16 + c0] = pp;
            }
        __syncthreads();
        if (tid < 128) {
            float s = 0.f;
#pragma unroll
            for (int j = 0; j < 32; ++j) s += red[tid * 33 + j];
            atomicAdd(&Yf[row0 + tid], s);
        }
    } else {
#pragma unroll
        for (int m = 0; m < 4; ++m)
#pragma unroll
            for (int r4 = 0; r4 < 4; ++r4) {
                int row = row0 + wr + m * 16 + q * 4 + r4;
#pragma unroll
                for (int n = 0; n < 4; ++n) {
                    int col = col0 + wc + n * 16 + c0;
                    float v = acc[m][n][r4] + bv[n];
                    if constexpr (MODE == 1) {
                        Yh[(size_t)row * 128 + col] = f2h(tanhfast(v));
                    } else if constexpr (MODE == 2) {
                        v = sigf(v);
                        if (row < Nc) {
                            Yh[(size_t)row * 128 + col] = f2h(v);
                        } else {
                            size_t o = (size_t)(row - Nc) * 128 + col;
                            float qe = h2f(QEp[o]), s3 = h2f(S3p[o]);
                            Yh[(size_t)row * 128 + col] = f2h(fmaf(v, s3, qe));
                        }
                    } else if constexpr (MODE == 3) {
                        size_t o = (size_t)row * 128 + col;
                        float tf = h2f(Yh[o]);   // read tf BEFORE overwriting with qp
                        float te = gtab[(size_t)idx[gmap(row, s0, CS)] * 128 + col];
                        AUX[(size_t)row * 384 + 256 + col] = f2h(fmaf(tf, te, v));
                        Yh[o] = f2h(v);
                    } else { // MODE 4
                        bool isE = (by < 2);
                        v = isE ? sigf(v) : tanhfast(v);
                        AUX[((size_t)row * 256 + col) * 2 + (isE ? 0 : 1)] = f2h(v);
                    }
                }
            }
    }
}

// ---------------------------------------------------------------------------
// w = softmax(qp @ Mk^T), qp fp16: one wave per row, lane m<50 does 128-dot
// ---------------------------------------------------------------------------
__global__ __launch_bounds__(256) void wsoftmax(
    const u16* __restrict__ QP, const float* __restrict__ Mk,
    float* __restrict__ Wb, int Nc)
{
    int gw = (blockIdx.x * 256 + threadIdx.x) >> 6;
    int lane = threadIdx.x & 63;
    if (gw >= Nc) return;
    const u16* qrow = QP + (size_t)gw * DQ;
    float logit = -3.0e38f;
    if (lane < MM) {
        const float* mk = Mk + lane * DQ;
        float s0 = 0.f, s1 = 0.f, s2 = 0.f, s3 = 0.f;
#pragma unroll
        for (int k = 0; k < DQ; k += 8) {
            half8 qv = *(const half8*)(qrow + k);
            float4 m0 = ld4(mk + k);
            float4 m1 = ld4(mk + k + 4);
            s0 = fmaf((float)qv[0], m0.x, s0); s1 = fmaf((float)qv[1], m0.y, s1);
            s2 = fmaf((float)qv[2], m0.z, s2); s3 = fmaf((float)qv[3], m0.w, s3);
            s0 = fmaf((float)qv[4], m1.x, s0); s1 = fmaf((float)qv[5], m1.y, s1);
            s2 = fmaf((float)qv[6], m1.z, s2); s3 = fmaf((float)qv[7], m1.w, s3);
        }
        logit = (s0 + s1) + (s2 + s3);
    }
    float mx = logit;
#pragma unroll
    for (int off = 32; off; off >>= 1) mx = fmaxf(mx, __shfl_xor(mx, off));
    float ex = (lane < MM) ? __expf(logit - mx) : 0.f;
    float sum = ex;
#pragma unroll
    for (int off = 32; off; off >>= 1) sum += __shfl_xor(sum, off);
    if (lane < MM) Wb[(size_t)gw * WSTRIDE + lane] = ex / sum;
}

// ---------------------------------------------------------------------------
// DKVMN scan: Mv in 50 regs/thread, ping-pong prefetch; e/a packed fp16,
// reads written as fp16 into RDIE[:, 0:256) (row stride 384).
// ---------------------------------------------------------------------------
__device__ __forceinline__ void load_w(float* w, const float* __restrict__ src) {
#pragma unroll
    for (int i = 0; i < 13; ++i) {
        float4 v = ld4(src + i * 4);
        w[i * 4 + 0] = v.x; w[i * 4 + 1] = v.y;
        w[i * 4 + 2] = v.z; w[i * 4 + 3] = v.w;
    }
}

__global__ __launch_bounds__(256) void scan_kernel(
    const float* __restrict__ Wb, const u32* __restrict__ EA,
    const float* __restrict__ Mv0, float* __restrict__ MvSt,
    u16* __restrict__ RDIE, int CS, int first)
{
    const int b = blockIdx.x;
    const int d = threadIdx.x;
    float mv[MM];
    if (first) {
#pragma unroll
        for (int m = 0; m < MM; ++m) mv[m] = Mv0[m * DV + d];
    } else {
#pragma unroll
        for (int m = 0; m < MM; ++m) mv[m] = MvSt[((size_t)b * MM + m) * DV + d];
    }

    const float* wrow = Wb + (size_t)b * CS * WSTRIDE;
    const u32* ep = EA + (size_t)b * CS * DV + d;
    u16* rp = RDIE + (size_t)b * CS * 384 + d;

    float wA[52], wB[52];
    u32 eaA, eaB;
    load_w(wA, wrow); eaA = *ep;

    for (int t = 0; t < CS; t += 2) {
        load_w(wB, wrow + WSTRIDE); eaB = ep[DV];
        {
            float e = h2f((u16)(eaA & 0xffff)), a = h2f((u16)(eaA >> 16));
            float r0 = 0.f, r1 = 0.f, r2 = 0.f, r3 = 0.f;
#pragma unroll
            for (int m = 0; m < 48; m += 4) {
                r0 = fmaf(wA[m + 0], mv[m + 0], r0);
                r1 = fmaf(wA[m + 1], mv[m + 1], r1);
                r2 = fmaf(wA[m + 2], mv[m + 2], r2);
                r3 = fmaf(wA[m + 3], mv[m + 3], r3);
            }
            r0 = fmaf(wA[48], mv[48], r0);
            r1 = fmaf(wA[49], mv[49], r1);
            *rp = f2h((r0 + r2) + (r1 + r3));
#pragma unroll
            for (int m = 0; m < MM; ++m) {
                float wm = wA[m];
                mv[m] = fmaf(mv[m], fmaf(-wm, e, 1.f), wm * a);
            }
        }
        wrow += 2 * WSTRIDE; ep += 2 * DV;
        if (t + 2 < CS) { load_w(wA, wrow); eaA = *ep; }
        {
            float e = h2f((u16)(eaB & 0xffff)), a = h2f((u16)(eaB >> 16));
            float r0 = 0.f, r1 = 0.f, r2 = 0.f, r3 = 0.f;
#pragma unroll
            for (int m = 0; m < 48; m += 4) {
                r0 = fmaf(wB[m + 0], mv[m + 0], r0);
                r1 = fmaf(wB[m + 1], mv[m + 1], r1);
                r2 = fmaf(wB[m + 2], mv[m + 2], r2);
                r3 = fmaf(wB[m + 3], mv[m + 3], r3);
            }
            r0 = fmaf(wB[48], mv[48], r0);
            r1 = fmaf(wB[49], mv[49], r1);
            rp[384] = f2h((r0 + r2) + (r1 + r3));
#pragma unroll
            for (int m = 0; m < MM; ++m) {
                float wm = wB[m];
                mv[m] = fmaf(mv[m], fmaf(-wm, e, 1.f), wm * a);
            }
        }
        rp += 2 * 384;
    }
#pragma unroll
    for (int m = 0; m < MM; ++m) MvSt[((size_t)b * MM + m) * DV + d] = mv[m];
}

// ---------------------------------------------------------------------------
// loss + outputs
// ---------------------------------------------------------------------------
__global__ __launch_bounds__(256) void loss_part(
    const float* __restrict__ P, const int* __restrict__ target,
    const float* __restrict__ pred_b, float* __restrict__ out,
    float* __restrict__ R2, int s0, int CS, int Nc)
{
    int l = blockIdx.x * 256 + threadIdx.x;
    float le = 0.f, mf = 0.f;
    if (l < Nc) {
        int n = gmap(l, s0, CS);
        float p = P[l] + pred_b[0];
        int t = target[n];
        float y = (t >= 1) ? (float)(t - 1) : 0.f;
        float sig = 1.f / (1.f + __expf(-p));
        if (t >= 1) {
            mf = 1.f;
            le = fmaxf(p, 0.f) + log1pf(__expf(-fabsf(p))) - p * y;
        }
        out[1 + n] = sig * mf;
        out[1 + NROWS + n] = y * mf;
    }
#pragma unroll
    for (int off = 32; off; off >>= 1) {
        le += __shfl_down(le, off);
        mf += __shfl_down(mf, off);
    }
    __shared__ float sl[4], sm[4];
    int wid = threadIdx.x >> 6;
    if ((threadIdx.x & 63) == 0) { sl[wid] = le; sm[wid] = mf; }
    __syncthreads();
    if (threadIdx.x == 0) {
        atomicAdd(R2, sl[0] + sl[1] + sl[2] + sl[3]);
        atomicAdd(R2 + 1, sm[0] + sm[1] + sm[2] + sm[3]);
    }
}

__global__ void loss_fin(const float* __restrict__ R2, float* __restrict__ out)
{
    out[0] = R2[0] / fmaxf(R2[1], 1.f);
}

// ---------------------------------------------------------------------------
extern "C" void kernel_launch(void* const* d_in, const int* in_sizes, int n_in,
                              void* d_out, int out_size, void* d_ws, size_t ws_size,
                              hipStream_t stream)
{
    const int* q_data       = (const int*)d_in[0];
    const int* qa_data      = (const int*)d_in[1];
    const int* target       = (const int*)d_in[2];
    const int* time_data    = (const int*)d_in[3];
    const int* attempt_data = (const int*)d_in[4];
    const int* hint_data    = (const int*)d_in[5];
    const int* hintT_data   = (const int*)d_in[6];
    const float* q_emb    = (const float*)d_in[7];
    const float* qa_emb   = (const float*)d_in[8];
    const float* time_emb = (const float*)d_in[9];
    const float* att_emb  = (const float*)d_in[10];
    const float* ht_emb   = (const float*)d_in[11];
    const float* Mk       = (const float*)d_in[12];
    const float* Mv0      = (const float*)d_in[13];
    const float* diff_W   = (const float*)d_in[14];
    const float* diff_b   = (const float*)d_in[15];
    const float* diff2_W  = (const float*)d_in[16];
    const float* diff2_b  = (const float*)d_in[17];
    const float* erase_W  = (const float*)d_in[18];
    const float* erase_b  = (const float*)d_in[19];
    const float* add_W    = (const float*)d_in[20];
    const float* add_b    = (const float*)d_in[21];
    const float* read_W   = (const float*)d_in[22];
    const float* read_b   = (const float*)d_in[23];
    const float* pred_W   = (const float*)d_in[24];
    const float* pred_b   = (const float*)d_in[25];
    float* out = (float*)d_out;
    (void)in_sizes; (void)n_in; (void)out_size;

    // Adaptive chunking over S. Per-chunk bytes = Nc*3028; fixed = 24,068,624.
    static const int cs_opts[] = {500, 250, 100, 50, 20, 10, 4, 2};
    const size_t FIXED = 13107216ull + 720896ull + 10240512ull;
    int CS = 0;
    for (int i = 0; i < 8; ++i) {
        size_t need = (size_t)NB * cs_opts[i] * 3028ull + FIXED;
        if (need <= ws_size) { CS = cs_opts[i]; break; }
    }
    if (CS == 0) return;
    const int NCH = SQ / CS;
    const int Nc = NB * CS;

    // Workspace layout (16B-aligned sections)
    float* MvSt  = (float*)d_ws;                         // [NB*MM*DV]
    float* wbuf  = MvSt + (size_t)NB * MM * DV;          // [Nc*52]
    float* bufP  = wbuf + (size_t)Nc * WSTRIDE;          // [Nc]
    float* bufR2 = bufP + Nc;                            // [4]
    u32*  EAu    = (u32*)(bufR2 + 4);                    // [Nc*256]
    u16*  Xp     = (u16*)(EAu + (size_t)Nc * 256);       // [2Nc*128]
    u16*  S3p    = Xp + (size_t)2 * Nc * 128;            // [Nc*128]
    u16*  QEp    = S3p + (size_t)Nc * 128;               // [Nc*128]
    u16*  RDIE   = QEp + (size_t)Nc * 128;               // [Nc*384]
    u16*  dWh    = RDIE + (size_t)Nc * 384;              // 16384
    u16*  d2Wh   = dWh + 16384;                          // 16384
    u16*  eWh    = d2Wh + 16384;                         // 65536
    u16*  aWh    = eWh + 65536;                          // 65536
    u16*  rWh    = aWh + 65536;                          // 196608
    u16*  qaEh   = rWh + 196608;                         // 5,120,256

    // One-time weight/table conversions to fp16
    cvt16<<<16, 256, 0, stream>>>(diff_W,  dWh,  16384 / 4);
    cvt16<<<16, 256, 0, stream>>>(diff2_W, d2Wh, 16384 / 4);
    cvt16<<<64, 256, 0, stream>>>(erase_W, eWh,  65536 / 4);
    cvt16<<<64, 256, 0, stream>>>(add_W,   aWh,  65536 / 4);
    cvt16<<<192, 256, 0, stream>>>(read_W, rWh,  196608 / 4);
    cvt16<<<5001, 256, 0, stream>>>(qa_emb, qaEh, 5120256 / 4);
    hipMemsetAsync(bufR2, 0, 4 * sizeof(float), stream);

    for (int c = 0; c < NCH; ++c) {
        const int s0 = c * CS;

        prep128<<<Nc / 8, 256, 0, stream>>>(
            q_data, time_data, attempt_data, hint_data, hintT_data,
            q_emb, time_emb, att_emb, ht_emb, Xp, S3p, QEp, s0, CS, Nc);

        // G1: [T1;T2] = tanh(lin1([X1;X2]))  (in-place Xp, 2Nc rows)
        gemm16<1><<<dim3(2 * Nc / 128, 1), 256, 0, stream>>>(
            Xp, dWh, nullptr, diff_b, nullptr, Xp, nullptr,
            nullptr, nullptr, nullptr, nullptr, nullptr, nullptr, 128, Nc, s0, CS);
        // G2: sig(lin2): rows<Nc -> tf; rows>=Nc -> x3 = qe + df*s3  (in-place)
        gemm16<2><<<dim3(2 * Nc / 128, 1), 256, 0, stream>>>(
            Xp, d2Wh, nullptr, diff2_b, nullptr, Xp, nullptr,
            QEp, S3p, nullptr, nullptr, nullptr, nullptr, 128, Nc, s0, CS);
        // G3: qp = lin1(x3) -> Xp[0:Nc); fused ie = qp + tf*te -> RDIE[:,256:)
        gemm16<3><<<dim3(Nc / 128, 1), 256, 0, stream>>>(
            Xp + (size_t)Nc * 128, dWh, nullptr, diff_b, nullptr, Xp, nullptr,
            nullptr, nullptr, time_data, time_emb, RDIE, nullptr, 128, Nc, s0, CS);
        // w = softmax(qp @ Mk^T)
        wsoftmax<<<Nc / 4, 256, 0, stream>>>(Xp, Mk, wbuf, Nc);
        // G4: e/a gates, gather-A from fp16 qa_emb, packed (e,a) -> EAu
        gemm16<4><<<dim3(Nc / 128, 4), 256, 0, stream>>>(
            qaEh, eWh, aWh, erase_b, add_b, nullptr, nullptr,
            nullptr, nullptr, qa_data, nullptr, (u16*)EAu, nullptr, 256, Nc, s0, CS);
        // scan -> RD fp16 into RDIE[:,0:256)
        scan_kernel<<<NB, DV, 0, stream>>>(wbuf, EAu, Mv0, MvSt, RDIE, CS, c == 0 ? 1 : 0);

        hipMemsetAsync(bufP, 0, (size_t)Nc * sizeof(float), stream);
        // G5: rc = tanh([rd|ie] @ read_W^T + b); pred partials -> bufP
        gemm16<5><<<dim3(Nc / 128, 4), 256, 0, stream>>>(
            RDIE, rWh, nullptr, read_b, nullptr, nullptr, bufP,
            nullptr, nullptr, nullptr, nullptr, nullptr, pred_W, 384, Nc, s0, CS);

        loss_part<<<Nc / 256, 256, 0, stream>>>(bufP, target, pred_b, out, bufR2, s0, CS, Nc);
    }

    loss_fin<<<1, 1, 0, stream>>>(bufR2, out);
}

// Round 5
// 1244.179 us; speedup vs baseline: 2.4473x; 1.2271x over previous
//
#include <hip/hip_runtime.h>
#include <cstdint>
#include <cstddef>

// Problem constants
#define NB 256
#define SQ 500
#define NROWS (NB * SQ)   // 128000
#define DQ 128
#define DV 256
#define MM 50
#define FF 512
#define WSTRIDE 52        // padded w-row stride (16B aligned)
#define WT 10             // scan LDS tile: steps per stage (divides all CS options)

typedef _Float16 half8 __attribute__((ext_vector_type(8)));
typedef float floatx4 __attribute__((ext_vector_type(4)));
typedef unsigned short u16;
typedef unsigned int u32;

__device__ __forceinline__ float4 ld4(const float* p) {
    return *reinterpret_cast<const float4*>(p);
}
__device__ __forceinline__ float sigf(float x) { return 1.f / (1.f + __expf(-x)); }
__device__ __forceinline__ float tanhfast(float x) { return 2.f / (1.f + __expf(-2.f * x)) - 1.f; }
__device__ __forceinline__ int gmap(int l, int s0, int CS) {
    int b = (unsigned)l / (unsigned)CS;
    return b * SQ + s0 + (l - b * CS);
}
__device__ __forceinline__ void st4h(u16* dst, float4 v) {
    _Float16 h0 = (_Float16)v.x, h1 = (_Float16)v.y, h2 = (_Float16)v.z, h3 = (_Float16)v.w;
    ushort4 u;
    u.x = *(u16*)&h0; u.y = *(u16*)&h1; u.z = *(u16*)&h2; u.w = *(u16*)&h3;
    *(ushort4*)dst = u;
}
__device__ __forceinline__ float h2f(u16 b) { _Float16 h; *(u16*)&h = b; return (float)h; }
__device__ __forceinline__ u16 f2h(float x) { _Float16 h = (_Float16)x; return *(u16*)&h; }

// ---------------------------------------------------------------------------
// fp32 -> fp16 conversion (vec4)
// ---------------------------------------------------------------------------
__global__ __launch_bounds__(256) void cvt16(
    const float* __restrict__ s, u16* __restrict__ d, int n4)
{
    int i = blockIdx.x * 256 + threadIdx.x;
    if (i < n4) st4h(d + 4 * (size_t)i, ld4(s + 4 * (size_t)i));
}

// ---------------------------------------------------------------------------
// prep: Xp rows [0,Nc) = fp16(te+qe); rows [Nc,2Nc) = fp16(he+hte+ae+qe);
//       S3p = fp16(he+hte+ae); QEp = fp16(qe)
// ---------------------------------------------------------------------------
__global__ __launch_bounds__(256) void prep128(
    const int* __restrict__ q_data, const int* __restrict__ time_data,
    const int* __restrict__ attempt_data, const int* __restrict__ hint_data,
    const int* __restrict__ hintT_data,
    const float* __restrict__ q_emb, const float* __restrict__ time_emb,
    const float* __restrict__ attempt_emb, const float* __restrict__ ht_emb,
    u16* __restrict__ Xp, u16* __restrict__ S3p, u16* __restrict__ QEp,
    int s0, int CS, int Nc)
{
    int g = blockIdx.x * 256 + threadIdx.x;
    int l = g >> 5;
    int kq = (g & 31) << 2;
    if (l >= Nc) return;
    int n = gmap(l, s0, CS);
    float4 qe  = ld4(q_emb       + (size_t)q_data[n]       * DQ + kq);
    float4 te  = ld4(time_emb    + (size_t)time_data[n]    * DQ + kq);
    float4 ae  = ld4(attempt_emb + (size_t)attempt_data[n] * DQ + kq);
    float4 he  = ld4(ht_emb      + (size_t)hint_data[n]    * DQ + kq);
    float4 hte = ld4(ht_emb      + (size_t)hintT_data[n]   * DQ + kq);
    size_t off = (size_t)l * DQ + kq;
    float4 x1, s3, x2;
    x1.x = te.x + qe.x; x1.y = te.y + qe.y; x1.z = te.z + qe.z; x1.w = te.w + qe.w;
    s3.x = he.x + hte.x + ae.x; s3.y = he.y + hte.y + ae.y;
    s3.z = he.z + hte.z + ae.z; s3.w = he.w + hte.w + ae.w;
    x2.x = s3.x + qe.x; x2.y = s3.y + qe.y; x2.z = s3.z + qe.z; x2.w = s3.w + qe.w;
    st4h(Xp + off, x1);
    st4h(Xp + (size_t)Nc * DQ + off, x2);
    st4h(S3p + off, s3);
    st4h(QEp + off, qe);
}

// ---------------------------------------------------------------------------
// fp16 MFMA GEMM: Y = epi(act(A @ W^T + bias)), BM=BN=128, BK=32, 4 waves,
// wave tile 64x64 = 4x4 of v_mfma_f32_16x16x32_f16.
// MODE 1: tanh -> fp16 Yh (stride 128)               [lin1 on 2Nc rows]
// MODE 2: sig; row<Nc: tf->Yh; row>=Nc: x3=qe+v*s3 -> Yh  [lin2 batched]
// MODE 3: none; qp->Yh; fused ie=qp+tf*te -> AUX[,256:384] [lin1(X3)+ew_ie]
// MODE 4: gather A=qaE[idx]; by<2: sig->e, else tanh->a; packed u16 pairs->AUX
// MODE 5: tanh(rc); pred-partial reduce -> atomicAdd Yf    [readout+pred]
// ---------------------------------------------------------------------------
template <int MODE>
__global__ __launch_bounds__(256, 3) void gemm16(
    const u16* __restrict__ A, const u16* __restrict__ W0,
    const u16* __restrict__ W1, const float* __restrict__ b0,
    const float* __restrict__ b1, u16* __restrict__ Yh,
    float* __restrict__ Yf,
    const u16* __restrict__ QEp, const u16* __restrict__ S3p,
    const int* __restrict__ idx, const float* __restrict__ gtab,
    u16* __restrict__ AUX, const float* __restrict__ predW,
    int K, int Nc, int s0, int CS)
{
    __shared__ u16 smem[2 * 128 * 40];   // 20480 B: A-tile | B-tile (pitch 80B)
    u16* At = smem;
    u16* Bt = smem + 128 * 40;
    const int tid = threadIdx.x;
    const int row0 = blockIdx.x * 128;
    const int by = blockIdx.y;

    const u16* Wp;
    int col0;
    if constexpr (MODE == 4) { Wp = (by < 2) ? W0 : W1; col0 = (by & 1) * 128; }
    else { Wp = W0; col0 = by * 128; }
    const float* bias = (MODE == 4 && by >= 2) ? b1 : b0;

    floatx4 acc[4][4];
#pragma unroll
    for (int m = 0; m < 4; ++m)
#pragma unroll
        for (int n = 0; n < 4; ++n) acc[m][n] = (floatx4)0.f;

    const int lane = tid & 63, wv = tid >> 6;
    const int wr = (wv >> 1) * 64, wc = (wv & 1) * 64;
    const int q = lane >> 4, c0 = lane & 15;

    for (int kt = 0; kt < K; kt += 32) {
#pragma unroll
        for (int i = 0; i < 4; ++i) {
            int c = tid + i * 256;          // [0,1024)
            if (c < 512) {
                int r = c >> 2, seg = c & 3;
                const u16* src;
                if constexpr (MODE == 4) {
                    int g = idx[gmap(row0 + r, s0, CS)];
                    src = A + (size_t)g * K + kt + seg * 8;
                } else {
                    src = A + (size_t)(row0 + r) * K + kt + seg * 8;
                }
                *(uint4*)&At[r * 40 + seg * 8] = *(const uint4*)src;
            } else {
                int cb = c - 512;
                int r = cb >> 2, seg = cb & 3;
                const u16* src = Wp + (size_t)(col0 + r) * K + kt + seg * 8;
                *(uint4*)&Bt[r * 40 + seg * 8] = *(const uint4*)src;
            }
        }
        __syncthreads();
        half8 af[4], bf[4];
#pragma unroll
        for (int m = 0; m < 4; ++m) af[m] = *(half8*)&At[(wr + m * 16 + c0) * 40 + q * 8];
#pragma unroll
        for (int n = 0; n < 4; ++n) bf[n] = *(half8*)&Bt[(wc + n * 16 + c0) * 40 + q * 8];
#pragma unroll
        for (int m = 0; m < 4; ++m)
#pragma unroll
            for (int n = 0; n < 4; ++n)
                acc[m][n] = __builtin_amdgcn_mfma_f32_16x16x32_f16(af[m], bf[n], acc[m][n], 0, 0, 0);
        __syncthreads();
    }

    float bv[4];
#pragma unroll
    for (int n = 0; n < 4; ++n) bv[n] = bias[col0 + wc + n * 16 + c0];

    if constexpr (MODE == 5) {
        float pw[4];
#pragma unroll
        for (int n = 0; n < 4; ++n) pw[n] = predW[col0 + wc + n * 16 + c0];
        float* red = (float*)smem;          // [128][33] = 16896 B <= 20480
#pragma unroll
        for (int m = 0; m < 4; ++m)
#pragma unroll
            for (int r4 = 0; r4 < 4; ++r4) {
                int row = wr + m * 16 + q * 4 + r4;
                float pp = 0.f;
#pragma unroll
                for (int n = 0; n < 4; ++n)
                    pp = fmaf(tanhfast(acc[m][n][r4] + bv[n]), pw[n], pp);
                red[row * 33 + (wv & 1) * 16 + c0] = pp;
            }
        __syncthreads();
        if (tid < 128) {
            float s = 0.f;
#pragma unroll
            for (int j = 0; j < 32; ++j) s += red[tid * 33 + j];
            atomicAdd(&Yf[row0 + tid], s);
        }
    } else {
#pragma unroll
        for (int m = 0; m < 4; ++m)
#pragma unroll
            for (int r4 = 0; r4 < 4; ++r4) {
                int row = row0 + wr + m * 16 + q * 4 + r4;
#pragma unroll
                for (int n = 0; n < 4; ++n) {
                    int col = col0 + wc + n * 16 + c0;
                    float v = acc[m][n][r4] + bv[n];
                    if constexpr (MODE == 1) {
                        Yh[(size_t)row * 128 + col] = f2h(tanhfast(v));
                    } else if constexpr (MODE == 2) {
                        v = sigf(v);
                        if (row < Nc) {
                            Yh[(size_t)row * 128 + col] = f2h(v);
                        } else {
                            size_t o = (size_t)(row - Nc) * 128 + col;
                            float qe = h2f(QEp[o]), s3 = h2f(S3p[o]);
                            Yh[(size_t)row * 128 + col] = f2h(fmaf(v, s3, qe));
                        }
                    } else if constexpr (MODE == 3) {
                        size_t o = (size_t)row * 128 + col;
                        float tf = h2f(Yh[o]);   // read tf BEFORE overwriting with qp
                        float te = gtab[(size_t)idx[gmap(row, s0, CS)] * 128 + col];
                        AUX[(size_t)row * 384 + 256 + col] = f2h(fmaf(tf, te, v));
                        Yh[o] = f2h(v);
                    } else { // MODE 4
                        bool isE = (by < 2);
                        v = isE ? sigf(v) : tanhfast(v);
                        AUX[((size_t)row * 256 + col) * 2 + (isE ? 0 : 1)] = f2h(v);
                    }
                }
            }
    }
}

// ---------------------------------------------------------------------------
// w = softmax(qp @ Mk^T), qp fp16: one wave per row, lane m<50 does 128-dot
// ---------------------------------------------------------------------------
__global__ __launch_bounds__(256) void wsoftmax(
    const u16* __restrict__ QP, const float* __restrict__ Mk,
    float* __restrict__ Wb, int Nc)
{
    int gw = (blockIdx.x * 256 + threadIdx.x) >> 6;
    int lane = threadIdx.x & 63;
    if (gw >= Nc) return;
    const u16* qrow = QP + (size_t)gw * DQ;
    float logit = -3.0e38f;
    if (lane < MM) {
        const float* mk = Mk + lane * DQ;
        float s0 = 0.f, s1 = 0.f, s2 = 0.f, s3 = 0.f;
#pragma unroll
        for (int k = 0; k < DQ; k += 8) {
            half8 qv = *(const half8*)(qrow + k);
            float4 m0 = ld4(mk + k);
            float4 m1 = ld4(mk + k + 4);
            s0 = fmaf((float)qv[0], m0.x, s0); s1 = fmaf((float)qv[1], m0.y, s1);
            s2 = fmaf((float)qv[2], m0.z, s2); s3 = fmaf((float)qv[3], m0.w, s3);
            s0 = fmaf((float)qv[4], m1.x, s0); s1 = fmaf((float)qv[5], m1.y, s1);
            s2 = fmaf((float)qv[6], m1.z, s2); s3 = fmaf((float)qv[7], m1.w, s3);
        }
        logit = (s0 + s1) + (s2 + s3);
    }
    float mx = logit;
#pragma unroll
    for (int off = 32; off; off >>= 1) mx = fmaxf(mx, __shfl_xor(mx, off));
    float ex = (lane < MM) ? __expf(logit - mx) : 0.f;
    float sum = ex;
#pragma unroll
    for (int off = 32; off; off >>= 1) sum += __shfl_xor(sum, off);
    if (lane < MM) Wb[(size_t)gw * WSTRIDE + lane] = ex / sum;
}

// ---------------------------------------------------------------------------
// DKVMN scan v2: 256 blocks (batch b) x 256 threads (dim d).
// w staged in LDS (double-buffered WT-step tiles; block-uniform rows are
// broadcast ds_reads). e/a prefetched per-tile into regs. Mv in 50 regs.
// ---------------------------------------------------------------------------
__global__ __launch_bounds__(256, 1) void scan_kernel(
    const float* __restrict__ Wb, const u32* __restrict__ EA,
    const float* __restrict__ Mv0, float* __restrict__ MvSt,
    u16* __restrict__ RDIE, int CS, int first)
{
    __shared__ float wt[2][WT * WSTRIDE];   // 2 x 520 floats = 4160 B
    const int b = blockIdx.x;
    const int d = threadIdx.x;

    float mv[MM];
    if (first) {
#pragma unroll
        for (int m = 0; m < MM; ++m) mv[m] = Mv0[m * DV + d];
    } else {
#pragma unroll
        for (int m = 0; m < MM; ++m) mv[m] = MvSt[((size_t)b * MM + m) * DV + d];
    }

    const float* wbase = Wb + (size_t)b * CS * WSTRIDE;   // rows contiguous
    const u32* ep = EA + (size_t)b * CS * DV + d;
    u16* rp = RDIE + (size_t)b * CS * 384 + d;

    const int NT = CS / WT;
    const bool loader = (d < (WT * WSTRIDE / 4));   // 130 loader threads

    // Preload tile 0: W -> LDS buf0, e/a -> regs
    if (loader) *(float4*)&wt[0][d * 4] = ld4(wbase + d * 4);
    u32 ea[WT];
#pragma unroll
    for (int i = 0; i < WT; ++i) ea[i] = ep[i * DV];
    __syncthreads();

    int cur = 0;
    for (int tile = 0; tile < NT; ++tile) {
        // Prefetch next tile (global -> regs); consumed after this tile's compute
        float4 wreg;
        u32 ean[WT];
        const bool havenext = (tile + 1 < NT);
        if (havenext) {
            if (loader) wreg = ld4(wbase + (size_t)(tile + 1) * WT * WSTRIDE + d * 4);
#pragma unroll
            for (int i = 0; i < WT; ++i) ean[i] = ep[(WT + i) * DV];
        }

        // Compute WT steps from LDS buf `cur`
        for (int s = 0; s < WT; ++s) {
            const float* w = &wt[cur][s * WSTRIDE];
            const float e = h2f((u16)(ea[s] & 0xffff));
            const float a = h2f((u16)(ea[s] >> 16));
            // Pull full w row into regs first (13 broadcast ds_read_b128)
            float wl[52];
#pragma unroll
            for (int i = 0; i < 13; ++i) {
                float4 v = *(const float4*)&w[i * 4];
                wl[i * 4 + 0] = v.x; wl[i * 4 + 1] = v.y;
                wl[i * 4 + 2] = v.z; wl[i * 4 + 3] = v.w;
            }
            float r0 = 0.f, r1 = 0.f, r2 = 0.f, r3 = 0.f;
#pragma unroll
            for (int m = 0; m < 48; m += 4) {
                r0 = fmaf(wl[m + 0], mv[m + 0], r0);
                r1 = fmaf(wl[m + 1], mv[m + 1], r1);
                r2 = fmaf(wl[m + 2], mv[m + 2], r2);
                r3 = fmaf(wl[m + 3], mv[m + 3], r3);
            }
            r0 = fmaf(wl[48], mv[48], r0);
            r1 = fmaf(wl[49], mv[49], r1);
            rp[(size_t)s * 384] = f2h((r0 + r2) + (r1 + r3));
#pragma unroll
            for (int m = 0; m < MM; ++m) {
                float wm = wl[m];
                mv[m] = fmaf(mv[m], fmaf(-wm, e, 1.f), wm * a);
            }
        }

        ep += WT * DV;
        rp += (size_t)WT * 384;
        if (havenext) {
            if (loader) *(float4*)&wt[1 - cur][d * 4] = wreg;
#pragma unroll
            for (int i = 0; i < WT; ++i) ea[i] = ean[i];
            __syncthreads();
            cur = 1 - cur;
        }
    }
#pragma unroll
    for (int m = 0; m < MM; ++m) MvSt[((size_t)b * MM + m) * DV + d] = mv[m];
}

// ---------------------------------------------------------------------------
// loss + outputs
// ---------------------------------------------------------------------------
__global__ __launch_bounds__(256) void loss_part(
    const float* __restrict__ P, const int* __restrict__ target,
    const float* __restrict__ pred_b, float* __restrict__ out,
    float* __restrict__ R2, int s0, int CS, int Nc)
{
    int l = blockIdx.x * 256 + threadIdx.x;
    float le = 0.f, mf = 0.f;
    if (l < Nc) {
        int n = gmap(l, s0, CS);
        float p = P[l] + pred_b[0];
        int t = target[n];
        float y = (t >= 1) ? (float)(t - 1) : 0.f;
        float sig = 1.f / (1.f + __expf(-p));
        if (t >= 1) {
            mf = 1.f;
            le = fmaxf(p, 0.f) + log1pf(__expf(-fabsf(p))) - p * y;
        }
        out[1 + n] = sig * mf;
        out[1 + NROWS + n] = y * mf;
    }
#pragma unroll
    for (int off = 32; off; off >>= 1) {
        le += __shfl_down(le, off);
        mf += __shfl_down(mf, off);
    }
    __shared__ float sl[4], sm[4];
    int wid = threadIdx.x >> 6;
    if ((threadIdx.x & 63) == 0) { sl[wid] = le; sm[wid] = mf; }
    __syncthreads();
    if (threadIdx.x == 0) {
        atomicAdd(R2, sl[0] + sl[1] + sl[2] + sl[3]);
        atomicAdd(R2 + 1, sm[0] + sm[1] + sm[2] + sm[3]);
    }
}

__global__ void loss_fin(const float* __restrict__ R2, float* __restrict__ out)
{
    out[0] = R2[0] / fmaxf(R2[1], 1.f);
}

// ---------------------------------------------------------------------------
extern "C" void kernel_launch(void* const* d_in, const int* in_sizes, int n_in,
                              void* d_out, int out_size, void* d_ws, size_t ws_size,
                              hipStream_t stream)
{
    const int* q_data       = (const int*)d_in[0];
    const int* qa_data      = (const int*)d_in[1];
    const int* target       = (const int*)d_in[2];
    const int* time_data    = (const int*)d_in[3];
    const int* attempt_data = (const int*)d_in[4];
    const int* hint_data    = (const int*)d_in[5];
    const int* hintT_data   = (const int*)d_in[6];
    const float* q_emb    = (const float*)d_in[7];
    const float* qa_emb   = (const float*)d_in[8];
    const float* time_emb = (const float*)d_in[9];
    const float* att_emb  = (const float*)d_in[10];
    const float* ht_emb   = (const float*)d_in[11];
    const float* Mk       = (const float*)d_in[12];
    const float* Mv0      = (const float*)d_in[13];
    const float* diff_W   = (const float*)d_in[14];
    const float* diff_b   = (const float*)d_in[15];
    const float* diff2_W  = (const float*)d_in[16];
    const float* diff2_b  = (const float*)d_in[17];
    const float* erase_W  = (const float*)d_in[18];
    const float* erase_b  = (const float*)d_in[19];
    const float* add_W    = (const float*)d_in[20];
    const float* add_b    = (const float*)d_in[21];
    const float* read_W   = (const float*)d_in[22];
    const float* read_b   = (const float*)d_in[23];
    const float* pred_W   = (const float*)d_in[24];
    const float* pred_b   = (const float*)d_in[25];
    float* out = (float*)d_out;
    (void)in_sizes; (void)n_in; (void)out_size;

    // Adaptive chunking over S (CS must be divisible by WT=10).
    static const int cs_opts[] = {500, 250, 100, 50, 20, 10};
    const size_t FIXED = 13107216ull + 720896ull + 10240512ull;
    int CS = 0;
    for (int i = 0; i < 6; ++i) {
        size_t need = (size_t)NB * cs_opts[i] * 3028ull + FIXED;
        if (need <= ws_size) { CS = cs_opts[i]; break; }
    }
    if (CS == 0) return;
    const int NCH = SQ / CS;
    const int Nc = NB * CS;

    // Workspace layout (16B-aligned sections)
    float* MvSt  = (float*)d_ws;                         // [NB*MM*DV]
    float* wbuf  = MvSt + (size_t)NB * MM * DV;          // [Nc*52]
    float* bufP  = wbuf + (size_t)Nc * WSTRIDE;          // [Nc]
    float* bufR2 = bufP + Nc;                            // [4]
    u32*  EAu    = (u32*)(bufR2 + 4);                    // [Nc*256]
    u16*  Xp     = (u16*)(EAu + (size_t)Nc * 256);       // [2Nc*128]
    u16*  S3p    = Xp + (size_t)2 * Nc * 128;            // [Nc*128]
    u16*  QEp    = S3p + (size_t)Nc * 128;               // [Nc*128]
    u16*  RDIE   = QEp + (size_t)Nc * 128;               // [Nc*384]
    u16*  dWh    = RDIE + (size_t)Nc * 384;              // 16384
    u16*  d2Wh   = dWh + 16384;                          // 16384
    u16*  eWh    = d2Wh + 16384;                         // 65536
    u16*  aWh    = eWh + 65536;                          // 65536
    u16*  rWh    = aWh + 65536;                          // 196608
    u16*  qaEh   = rWh + 196608;                         // 5,120,256

    // One-time weight/table conversions to fp16
    cvt16<<<16, 256, 0, stream>>>(diff_W,  dWh,  16384 / 4);
    cvt16<<<16, 256, 0, stream>>>(diff2_W, d2Wh, 16384 / 4);
    cvt16<<<64, 256, 0, stream>>>(erase_W, eWh,  65536 / 4);
    cvt16<<<64, 256, 0, stream>>>(add_W,   aWh,  65536 / 4);
    cvt16<<<192, 256, 0, stream>>>(read_W, rWh,  196608 / 4);
    cvt16<<<5001, 256, 0, stream>>>(qa_emb, qaEh, 5120256 / 4);
    hipMemsetAsync(bufR2, 0, 4 * sizeof(float), stream);

    for (int c = 0; c < NCH; ++c) {
        const int s0 = c * CS;

        prep128<<<Nc / 8, 256, 0, stream>>>(
            q_data, time_data, attempt_data, hint_data, hintT_data,
            q_emb, time_emb, att_emb, ht_emb, Xp, S3p, QEp, s0, CS, Nc);

        // G1: [T1;T2] = tanh(lin1([X1;X2]))  (in-place Xp, 2Nc rows)
        gemm16<1><<<dim3(2 * Nc / 128, 1), 256, 0, stream>>>(
            Xp, dWh, nullptr, diff_b, nullptr, Xp, nullptr,
            nullptr, nullptr, nullptr, nullptr, nullptr, nullptr, 128, Nc, s0, CS);
        // G2: sig(lin2): rows<Nc -> tf; rows>=Nc -> x3 = qe + df*s3  (in-place)
        gemm16<2><<<dim3(2 * Nc / 128, 1), 256, 0, stream>>>(
            Xp, d2Wh, nullptr, diff2_b, nullptr, Xp, nullptr,
            QEp, S3p, nullptr, nullptr, nullptr, nullptr, 128, Nc, s0, CS);
        // G3: qp = lin1(x3) -> Xp[0:Nc); fused ie = qp + tf*te -> RDIE[:,256:)
        gemm16<3><<<dim3(Nc / 128, 1), 256, 0, stream>>>(
            Xp + (size_t)Nc * 128, dWh, nullptr, diff_b, nullptr, Xp, nullptr,
            nullptr, nullptr, time_data, time_emb, RDIE, nullptr, 128, Nc, s0, CS);
        // w = softmax(qp @ Mk^T)
        wsoftmax<<<Nc / 4, 256, 0, stream>>>(Xp, Mk, wbuf, Nc);
        // G4: e/a gates, gather-A from fp16 qa_emb, packed (e,a) -> EAu
        gemm16<4><<<dim3(Nc / 128, 4), 256, 0, stream>>>(
            qaEh, eWh, aWh, erase_b, add_b, nullptr, nullptr,
            nullptr, nullptr, qa_data, nullptr, (u16*)EAu, nullptr, 256, Nc, s0, CS);
        // scan -> RD fp16 into RDIE[:,0:256)
        scan_kernel<<<NB, DV, 0, stream>>>(wbuf, EAu, Mv0, MvSt, RDIE, CS, c == 0 ? 1 : 0);

        hipMemsetAsync(bufP, 0, (size_t)Nc * sizeof(float), stream);
        // G5: rc = tanh([rd|ie] @ read_W^T + b); pred partials -> bufP
        gemm16<5><<<dim3(Nc / 128, 4), 256, 0, stream>>>(
            RDIE, rWh, nullptr, read_b, nullptr, nullptr, bufP,
            nullptr, nullptr, nullptr, nullptr, nullptr, pred_W, 384, Nc, s0, CS);

        loss_part<<<Nc / 256, 256, 0, stream>>>(bufP, target, pred_b, out, bufR2, s0, CS, Nc);
    }

    loss_fin<<<1, 1, 0, stream>>>(bufR2, out);
}

// Round 6
// 847.651 us; speedup vs baseline: 3.5921x; 1.4678x over previous
//
#include <hip/hip_runtime.h>
#include <cstdint>
#include <cstddef>

// Problem constants
#define NB 256
#define SQ 500
#define NROWS (NB * SQ)   // 128000
#define DQ 128
#define DV 256
#define MM 50
#define FF 512
#define WSTRIDE 52        // padded w-row stride (16B aligned)
#define WT 10             // scan LDS tile: steps per stage (divides all CS options)

typedef _Float16 half8 __attribute__((ext_vector_type(8)));
typedef float floatx4 __attribute__((ext_vector_type(4)));
typedef unsigned short u16;
typedef unsigned int u32;

__device__ __forceinline__ float4 ld4(const float* p) {
    return *reinterpret_cast<const float4*>(p);
}
__device__ __forceinline__ float sigf(float x) { return 1.f / (1.f + __expf(-x)); }
__device__ __forceinline__ float tanhfast(float x) { return 2.f / (1.f + __expf(-2.f * x)) - 1.f; }
__device__ __forceinline__ int gmap(int l, int s0, int CS) {
    int b = (unsigned)l / (unsigned)CS;
    return b * SQ + s0 + (l - b * CS);
}
__device__ __forceinline__ void st4h(u16* dst, float4 v) {
    _Float16 h0 = (_Float16)v.x, h1 = (_Float16)v.y, h2 = (_Float16)v.z, h3 = (_Float16)v.w;
    ushort4 u;
    u.x = *(u16*)&h0; u.y = *(u16*)&h1; u.z = *(u16*)&h2; u.w = *(u16*)&h3;
    *(ushort4*)dst = u;
}
__device__ __forceinline__ float h2f(u16 b) { _Float16 h; *(u16*)&h = b; return (float)h; }
__device__ __forceinline__ u16 f2h(float x) { _Float16 h = (_Float16)x; return *(u16*)&h; }

// ---------------------------------------------------------------------------
// fp32 -> fp16 conversion (vec4)
// ---------------------------------------------------------------------------
__global__ __launch_bounds__(256) void cvt16(
    const float* __restrict__ s, u16* __restrict__ d, int n4)
{
    int i = blockIdx.x * 256 + threadIdx.x;
    if (i < n4) st4h(d + 4 * (size_t)i, ld4(s + 4 * (size_t)i));
}

// ---------------------------------------------------------------------------
// Mk [50,128] fp32 -> Mkh [64,128] fp16, rows 50..63 zeroed
// ---------------------------------------------------------------------------
__global__ __launch_bounds__(256) void mkcvt(
    const float* __restrict__ Mk, u16* __restrict__ Mkh)
{
    int i = blockIdx.x * 256 + threadIdx.x;   // 2048 float4 slots
    if (i >= 64 * 32) return;
    int row = i >> 5;
    float4 v = (row < MM) ? ld4(Mk + (size_t)row * DQ + (i & 31) * 4)
                          : float4{0.f, 0.f, 0.f, 0.f};
    st4h(Mkh + 4 * (size_t)i, v);
}

// ---------------------------------------------------------------------------
// prep: Xp rows [0,Nc) = fp16(te+qe); rows [Nc,2Nc) = fp16(he+hte+ae+qe);
//       S3p = fp16(he+hte+ae); QEp = fp16(qe)
// ---------------------------------------------------------------------------
__global__ __launch_bounds__(256) void prep128(
    const int* __restrict__ q_data, const int* __restrict__ time_data,
    const int* __restrict__ attempt_data, const int* __restrict__ hint_data,
    const int* __restrict__ hintT_data,
    const float* __restrict__ q_emb, const float* __restrict__ time_emb,
    const float* __restrict__ attempt_emb, const float* __restrict__ ht_emb,
    u16* __restrict__ Xp, u16* __restrict__ S3p, u16* __restrict__ QEp,
    int s0, int CS, int Nc)
{
    int g = blockIdx.x * 256 + threadIdx.x;
    int l = g >> 5;
    int kq = (g & 31) << 2;
    if (l >= Nc) return;
    int n = gmap(l, s0, CS);
    float4 qe  = ld4(q_emb       + (size_t)q_data[n]       * DQ + kq);
    float4 te  = ld4(time_emb    + (size_t)time_data[n]    * DQ + kq);
    float4 ae  = ld4(attempt_emb + (size_t)attempt_data[n] * DQ + kq);
    float4 he  = ld4(ht_emb      + (size_t)hint_data[n]    * DQ + kq);
    float4 hte = ld4(ht_emb      + (size_t)hintT_data[n]   * DQ + kq);
    size_t off = (size_t)l * DQ + kq;
    float4 x1, s3, x2;
    x1.x = te.x + qe.x; x1.y = te.y + qe.y; x1.z = te.z + qe.z; x1.w = te.w + qe.w;
    s3.x = he.x + hte.x + ae.x; s3.y = he.y + hte.y + ae.y;
    s3.z = he.z + hte.z + ae.z; s3.w = he.w + hte.w + ae.w;
    x2.x = s3.x + qe.x; x2.y = s3.y + qe.y; x2.z = s3.z + qe.z; x2.w = s3.w + qe.w;
    st4h(Xp + off, x1);
    st4h(Xp + (size_t)Nc * DQ + off, x2);
    st4h(S3p + off, s3);
    st4h(QEp + off, qe);
}

// ---------------------------------------------------------------------------
// fp16 MFMA GEMM: Y = epi(act(A @ W^T + bias)), BM=BN=128, BK=32, 4 waves,
// wave tile 64x64 = 4x4 of v_mfma_f32_16x16x32_f16.
// MODE 1: tanh -> fp16 Yh (stride 128)               [lin1 on 2Nc rows]
// MODE 2: sig; row<Nc: tf->Yh; row>=Nc: x3=qe+v*s3 -> Yh  [lin2 batched]
// MODE 3: none; qp->Yh; fused ie=qp+tf*te -> AUX[,256:384] [lin1(X3)+ew_ie]
// MODE 4: gather A=qaE[idx]; by<2: sig->e, else tanh->a; packed u16 pairs->AUX
// MODE 5: tanh(rc); pred-partial reduce -> atomicAdd Yf    [readout+pred]
// ---------------------------------------------------------------------------
template <int MODE>
__global__ __launch_bounds__(256, 3) void gemm16(
    const u16* __restrict__ A, const u16* __restrict__ W0,
    const u16* __restrict__ W1, const float* __restrict__ b0,
    const float* __restrict__ b1, u16* __restrict__ Yh,
    float* __restrict__ Yf,
    const u16* __restrict__ QEp, const u16* __restrict__ S3p,
    const int* __restrict__ idx, const float* __restrict__ gtab,
    u16* __restrict__ AUX, const float* __restrict__ predW,
    int K, int Nc, int s0, int CS)
{
    __shared__ u16 smem[2 * 128 * 40];   // 20480 B: A-tile | B-tile (pitch 80B)
    u16* At = smem;
    u16* Bt = smem + 128 * 40;
    const int tid = threadIdx.x;
    const int row0 = blockIdx.x * 128;
    const int by = blockIdx.y;

    const u16* Wp;
    int col0;
    if constexpr (MODE == 4) { Wp = (by < 2) ? W0 : W1; col0 = (by & 1) * 128; }
    else { Wp = W0; col0 = by * 128; }
    const float* bias = (MODE == 4 && by >= 2) ? b1 : b0;

    floatx4 acc[4][4];
#pragma unroll
    for (int m = 0; m < 4; ++m)
#pragma unroll
        for (int n = 0; n < 4; ++n) acc[m][n] = (floatx4)0.f;

    const int lane = tid & 63, wv = tid >> 6;
    const int wr = (wv >> 1) * 64, wc = (wv & 1) * 64;
    const int q = lane >> 4, c0 = lane & 15;

    for (int kt = 0; kt < K; kt += 32) {
#pragma unroll
        for (int i = 0; i < 4; ++i) {
            int c = tid + i * 256;          // [0,1024)
            if (c < 512) {
                int r = c >> 2, seg = c & 3;
                const u16* src;
                if constexpr (MODE == 4) {
                    int g = idx[gmap(row0 + r, s0, CS)];
                    src = A + (size_t)g * K + kt + seg * 8;
                } else {
                    src = A + (size_t)(row0 + r) * K + kt + seg * 8;
                }
                *(uint4*)&At[r * 40 + seg * 8] = *(const uint4*)src;
            } else {
                int cb = c - 512;
                int r = cb >> 2, seg = cb & 3;
                const u16* src = Wp + (size_t)(col0 + r) * K + kt + seg * 8;
                *(uint4*)&Bt[r * 40 + seg * 8] = *(const uint4*)src;
            }
        }
        __syncthreads();
        half8 af[4], bf[4];
#pragma unroll
        for (int m = 0; m < 4; ++m) af[m] = *(half8*)&At[(wr + m * 16 + c0) * 40 + q * 8];
#pragma unroll
        for (int n = 0; n < 4; ++n) bf[n] = *(half8*)&Bt[(wc + n * 16 + c0) * 40 + q * 8];
#pragma unroll
        for (int m = 0; m < 4; ++m)
#pragma unroll
            for (int n = 0; n < 4; ++n)
                acc[m][n] = __builtin_amdgcn_mfma_f32_16x16x32_f16(af[m], bf[n], acc[m][n], 0, 0, 0);
        __syncthreads();
    }

    float bv[4];
#pragma unroll
    for (int n = 0; n < 4; ++n) bv[n] = bias[col0 + wc + n * 16 + c0];

    if constexpr (MODE == 5) {
        float pw[4];
#pragma unroll
        for (int n = 0; n < 4; ++n) pw[n] = predW[col0 + wc + n * 16 + c0];
        float* red = (float*)smem;          // [128][33] = 16896 B <= 20480
#pragma unroll
        for (int m = 0; m < 4; ++m)
#pragma unroll
            for (int r4 = 0; r4 < 4; ++r4) {
                int row = wr + m * 16 + q * 4 + r4;
                float pp = 0.f;
#pragma unroll
                for (int n = 0; n < 4; ++n)
                    pp = fmaf(tanhfast(acc[m][n][r4] + bv[n]), pw[n], pp);
                red[row * 33 + (wv & 1) * 16 + c0] = pp;
            }
        __syncthreads();
        if (tid < 128) {
            float s = 0.f;
#pragma unroll
            for (int j = 0; j < 32; ++j) s += red[tid * 33 + j];
            atomicAdd(&Yf[row0 + tid], s);
        }
    } else {
#pragma unroll
        for (int m = 0; m < 4; ++m)
#pragma unroll
            for (int r4 = 0; r4 < 4; ++r4) {
                int row = row0 + wr + m * 16 + q * 4 + r4;
#pragma unroll
                for (int n = 0; n < 4; ++n) {
                    int col = col0 + wc + n * 16 + c0;
                    float v = acc[m][n][r4] + bv[n];
                    if constexpr (MODE == 1) {
                        Yh[(size_t)row * 128 + col] = f2h(tanhfast(v));
                    } else if constexpr (MODE == 2) {
                        v = sigf(v);
                        if (row < Nc) {
                            Yh[(size_t)row * 128 + col] = f2h(v);
                        } else {
                            size_t o = (size_t)(row - Nc) * 128 + col;
                            float qe = h2f(QEp[o]), s3 = h2f(S3p[o]);
                            Yh[(size_t)row * 128 + col] = f2h(fmaf(v, s3, qe));
                        }
                    } else if constexpr (MODE == 3) {
                        size_t o = (size_t)row * 128 + col;
                        float tf = h2f(Yh[o]);   // read tf BEFORE overwriting with qp
                        float te = gtab[(size_t)idx[gmap(row, s0, CS)] * 128 + col];
                        AUX[(size_t)row * 384 + 256 + col] = f2h(fmaf(tf, te, v));
                        Yh[o] = f2h(v);
                    } else { // MODE 4
                        bool isE = (by < 2);
                        v = isE ? sigf(v) : tanhfast(v);
                        AUX[((size_t)row * 256 + col) * 2 + (isE ? 0 : 1)] = f2h(v);
                    }
                }
            }
    }
}

// ---------------------------------------------------------------------------
// w = softmax(qp @ Mk^T) via MFMA. Block: 128 rows x 64 cols (50 live).
// Logits -> LDS (pitch 67: conflict-free column reads), row softmax,
// coalesced float4 store to Wb (stride WSTRIDE).
// ---------------------------------------------------------------------------
__global__ __launch_bounds__(256) void wsoftmax_mfma(
    const u16* __restrict__ QP, const u16* __restrict__ Mkh,
    float* __restrict__ Wb)
{
    __shared__ float Sred[128 * 67];        // 34304 B; head doubles as At/Bt
    u16* At = (u16*)Sred;                   // [128][40] fp16 = 10240 B
    u16* Bt = At + 128 * 40;                // [64][40]  fp16 =  5120 B
    const int tid = threadIdx.x;
    const int row0 = blockIdx.x * 128;
    const int lane = tid & 63, wv = tid >> 6;
    const int wr = wv * 32;                 // wave: 32 rows x 64 cols
    const int q = lane >> 4, c0 = lane & 15;

    floatx4 acc[2][4];
#pragma unroll
    for (int m = 0; m < 2; ++m)
#pragma unroll
        for (int n = 0; n < 4; ++n) acc[m][n] = (floatx4)0.f;

    for (int kt = 0; kt < DQ; kt += 32) {
#pragma unroll
        for (int i = 0; i < 3; ++i) {
            int c = tid + i * 256;          // [0,768)
            if (c < 512) {
                int r = c >> 2, seg = c & 3;
                *(uint4*)&At[r * 40 + seg * 8] =
                    *(const uint4*)(QP + (size_t)(row0 + r) * DQ + kt + seg * 8);
            } else {
                int cb = c - 512;
                int r = cb >> 2, seg = cb & 3;
                *(uint4*)&Bt[r * 40 + seg * 8] =
                    *(const uint4*)(Mkh + (size_t)r * DQ + kt + seg * 8);
            }
        }
        __syncthreads();
        half8 af[2], bf[4];
#pragma unroll
        for (int m = 0; m < 2; ++m) af[m] = *(half8*)&At[(wr + m * 16 + c0) * 40 + q * 8];
#pragma unroll
        for (int n = 0; n < 4; ++n) bf[n] = *(half8*)&Bt[(n * 16 + c0) * 40 + q * 8];
#pragma unroll
        for (int m = 0; m < 2; ++m)
#pragma unroll
            for (int n = 0; n < 4; ++n)
                acc[m][n] = __builtin_amdgcn_mfma_f32_16x16x32_f16(af[m], bf[n], acc[m][n], 0, 0, 0);
        __syncthreads();
    }

    // dump logits to LDS: row = wr + m*16 + q*4 + r, col = n*16 + c0
#pragma unroll
    for (int m = 0; m < 2; ++m)
#pragma unroll
        for (int r4 = 0; r4 < 4; ++r4) {
            int row = wr + m * 16 + q * 4 + r4;
#pragma unroll
            for (int n = 0; n < 4; ++n)
                Sred[row * 67 + n * 16 + c0] = acc[m][n][r4];
        }
    __syncthreads();

    // row-wise softmax over 50 live cols (one thread per row)
    if (tid < 128) {
        float* s = &Sred[tid * 67];
        float mx = -3.0e38f;
#pragma unroll
        for (int m = 0; m < MM; ++m) mx = fmaxf(mx, s[m]);
        float sum = 0.f;
#pragma unroll
        for (int m = 0; m < MM; ++m) { float e = __expf(s[m] - mx); s[m] = e; sum += e; }
        float inv = 1.f / sum;
#pragma unroll
        for (int m = 0; m < MM; ++m) s[m] *= inv;
        s[50] = 0.f; s[51] = 0.f;
    }
    __syncthreads();

    // coalesced store: 128 rows x 13 float4
    for (int i = tid; i < 128 * 13; i += 256) {
        int row = i / 13, seg = i - row * 13;
        float4 v;
        v.x = Sred[row * 67 + seg * 4 + 0];
        v.y = Sred[row * 67 + seg * 4 + 1];
        v.z = Sred[row * 67 + seg * 4 + 2];
        v.w = Sred[row * 67 + seg * 4 + 3];
        *(float4*)(Wb + (size_t)(row0 + row) * WSTRIDE + seg * 4) = v;
    }
}

// ---------------------------------------------------------------------------
// DKVMN scan v2: 256 blocks (batch b) x 256 threads (dim d).
// w staged in LDS (double-buffered WT-step tiles; block-uniform rows are
// broadcast ds_reads). e/a prefetched per-tile into regs. Mv in 50 regs.
// ---------------------------------------------------------------------------
__global__ __launch_bounds__(256, 1) void scan_kernel(
    const float* __restrict__ Wb, const u32* __restrict__ EA,
    const float* __restrict__ Mv0, float* __restrict__ MvSt,
    u16* __restrict__ RDIE, int CS, int first)
{
    __shared__ float wt[2][WT * WSTRIDE];   // 2 x 520 floats = 4160 B
    const int b = blockIdx.x;
    const int d = threadIdx.x;

    float mv[MM];
    if (first) {
#pragma unroll
        for (int m = 0; m < MM; ++m) mv[m] = Mv0[m * DV + d];
    } else {
#pragma unroll
        for (int m = 0; m < MM; ++m) mv[m] = MvSt[((size_t)b * MM + m) * DV + d];
    }

    const float* wbase = Wb + (size_t)b * CS * WSTRIDE;   // rows contiguous
    const u32* ep = EA + (size_t)b * CS * DV + d;
    u16* rp = RDIE + (size_t)b * CS * 384 + d;

    const int NT = CS / WT;
    const bool loader = (d < (WT * WSTRIDE / 4));   // 130 loader threads

    // Preload tile 0: W -> LDS buf0, e/a -> regs
    if (loader) *(float4*)&wt[0][d * 4] = ld4(wbase + d * 4);
    u32 ea[WT];
#pragma unroll
    for (int i = 0; i < WT; ++i) ea[i] = ep[i * DV];
    __syncthreads();

    int cur = 0;
    for (int tile = 0; tile < NT; ++tile) {
        // Prefetch next tile (global -> regs); consumed after this tile's compute
        float4 wreg;
        u32 ean[WT];
        const bool havenext = (tile + 1 < NT);
        if (havenext) {
            if (loader) wreg = ld4(wbase + (size_t)(tile + 1) * WT * WSTRIDE + d * 4);
#pragma unroll
            for (int i = 0; i < WT; ++i) ean[i] = ep[(WT + i) * DV];
        }

        // Compute WT steps from LDS buf `cur`
        for (int s = 0; s < WT; ++s) {
            const float* w = &wt[cur][s * WSTRIDE];
            const float e = h2f((u16)(ea[s] & 0xffff));
            const float a = h2f((u16)(ea[s] >> 16));
            // Pull full w row into regs first (13 broadcast ds_read_b128)
            float wl[52];
#pragma unroll
            for (int i = 0; i < 13; ++i) {
                float4 v = *(const float4*)&w[i * 4];
                wl[i * 4 + 0] = v.x; wl[i * 4 + 1] = v.y;
                wl[i * 4 + 2] = v.z; wl[i * 4 + 3] = v.w;
            }
            float r0 = 0.f, r1 = 0.f, r2 = 0.f, r3 = 0.f;
#pragma unroll
            for (int m = 0; m < 48; m += 4) {
                r0 = fmaf(wl[m + 0], mv[m + 0], r0);
                r1 = fmaf(wl[m + 1], mv[m + 1], r1);
                r2 = fmaf(wl[m + 2], mv[m + 2], r2);
                r3 = fmaf(wl[m + 3], mv[m + 3], r3);
            }
            r0 = fmaf(wl[48], mv[48], r0);
            r1 = fmaf(wl[49], mv[49], r1);
            rp[(size_t)s * 384] = f2h((r0 + r2) + (r1 + r3));
#pragma unroll
            for (int m = 0; m < MM; ++m) {
                float wm = wl[m];
                mv[m] = fmaf(mv[m], fmaf(-wm, e, 1.f), wm * a);
            }
        }

        ep += WT * DV;
        rp += (size_t)WT * 384;
        if (havenext) {
            if (loader) *(float4*)&wt[1 - cur][d * 4] = wreg;
#pragma unroll
            for (int i = 0; i < WT; ++i) ea[i] = ean[i];
            __syncthreads();
            cur = 1 - cur;
        }
    }
#pragma unroll
    for (int m = 0; m < MM; ++m) MvSt[((size_t)b * MM + m) * DV + d] = mv[m];
}

// ---------------------------------------------------------------------------
// loss + outputs
// ---------------------------------------------------------------------------
__global__ __launch_bounds__(256) void loss_part(
    const float* __restrict__ P, const int* __restrict__ target,
    const float* __restrict__ pred_b, float* __restrict__ out,
    float* __restrict__ R2, int s0, int CS, int Nc)
{
    int l = blockIdx.x * 256 + threadIdx.x;
    float le = 0.f, mf = 0.f;
    if (l < Nc) {
        int n = gmap(l, s0, CS);
        float p = P[l] + pred_b[0];
        int t = target[n];
        float y = (t >= 1) ? (float)(t - 1) : 0.f;
        float sig = 1.f / (1.f + __expf(-p));
        if (t >= 1) {
            mf = 1.f;
            le = fmaxf(p, 0.f) + log1pf(__expf(-fabsf(p))) - p * y;
        }
        out[1 + n] = sig * mf;
        out[1 + NROWS + n] = y * mf;
    }
#pragma unroll
    for (int off = 32; off; off >>= 1) {
        le += __shfl_down(le, off);
        mf += __shfl_down(mf, off);
    }
    __shared__ float sl[4], sm[4];
    int wid = threadIdx.x >> 6;
    if ((threadIdx.x & 63) == 0) { sl[wid] = le; sm[wid] = mf; }
    __syncthreads();
    if (threadIdx.x == 0) {
        atomicAdd(R2, sl[0] + sl[1] + sl[2] + sl[3]);
        atomicAdd(R2 + 1, sm[0] + sm[1] + sm[2] + sm[3]);
    }
}

__global__ void loss_fin(const float* __restrict__ R2, float* __restrict__ out)
{
    out[0] = R2[0] / fmaxf(R2[1], 1.f);
}

// ---------------------------------------------------------------------------
extern "C" void kernel_launch(void* const* d_in, const int* in_sizes, int n_in,
                              void* d_out, int out_size, void* d_ws, size_t ws_size,
                              hipStream_t stream)
{
    const int* q_data       = (const int*)d_in[0];
    const int* qa_data      = (const int*)d_in[1];
    const int* target       = (const int*)d_in[2];
    const int* time_data    = (const int*)d_in[3];
    const int* attempt_data = (const int*)d_in[4];
    const int* hint_data    = (const int*)d_in[5];
    const int* hintT_data   = (const int*)d_in[6];
    const float* q_emb    = (const float*)d_in[7];
    const float* qa_emb   = (const float*)d_in[8];
    const float* time_emb = (const float*)d_in[9];
    const float* att_emb  = (const float*)d_in[10];
    const float* ht_emb   = (const float*)d_in[11];
    const float* Mk       = (const float*)d_in[12];
    const float* Mv0      = (const float*)d_in[13];
    const float* diff_W   = (const float*)d_in[14];
    const float* diff_b   = (const float*)d_in[15];
    const float* diff2_W  = (const float*)d_in[16];
    const float* diff2_b  = (const float*)d_in[17];
    const float* erase_W  = (const float*)d_in[18];
    const float* erase_b  = (const float*)d_in[19];
    const float* add_W    = (const float*)d_in[20];
    const float* add_b    = (const float*)d_in[21];
    const float* read_W   = (const float*)d_in[22];
    const float* read_b   = (const float*)d_in[23];
    const float* pred_W   = (const float*)d_in[24];
    const float* pred_b   = (const float*)d_in[25];
    float* out = (float*)d_out;
    (void)in_sizes; (void)n_in; (void)out_size;

    // Adaptive chunking over S (CS must be divisible by WT=10).
    static const int cs_opts[] = {500, 250, 100, 50, 20, 10};
    const size_t FIXED = 13107216ull + 720896ull + 10240512ull + 16384ull;
    int CS = 0;
    for (int i = 0; i < 6; ++i) {
        size_t need = (size_t)NB * cs_opts[i] * 3028ull + FIXED;
        if (need <= ws_size) { CS = cs_opts[i]; break; }
    }
    if (CS == 0) return;
    const int NCH = SQ / CS;
    const int Nc = NB * CS;

    // Workspace layout (16B-aligned sections)
    float* MvSt  = (float*)d_ws;                         // [NB*MM*DV]
    float* wbuf  = MvSt + (size_t)NB * MM * DV;          // [Nc*52]
    float* bufP  = wbuf + (size_t)Nc * WSTRIDE;          // [Nc]
    float* bufR2 = bufP + Nc;                            // [4]
    u32*  EAu    = (u32*)(bufR2 + 4);                    // [Nc*256]
    u16*  Xp     = (u16*)(EAu + (size_t)Nc * 256);       // [2Nc*128]
    u16*  S3p    = Xp + (size_t)2 * Nc * 128;            // [Nc*128]
    u16*  QEp    = S3p + (size_t)Nc * 128;               // [Nc*128]
    u16*  RDIE   = QEp + (size_t)Nc * 128;               // [Nc*384]
    u16*  dWh    = RDIE + (size_t)Nc * 384;              // 16384
    u16*  d2Wh   = dWh + 16384;                          // 16384
    u16*  eWh    = d2Wh + 16384;                         // 65536
    u16*  aWh    = eWh + 65536;                          // 65536
    u16*  rWh    = aWh + 65536;                          // 196608
    u16*  qaEh   = rWh + 196608;                         // 5,120,256
    u16*  Mkh    = qaEh + 5120256;                       // 8,192 (64x128)

    // One-time weight/table conversions to fp16
    cvt16<<<16, 256, 0, stream>>>(diff_W,  dWh,  16384 / 4);
    cvt16<<<16, 256, 0, stream>>>(diff2_W, d2Wh, 16384 / 4);
    cvt16<<<64, 256, 0, stream>>>(erase_W, eWh,  65536 / 4);
    cvt16<<<64, 256, 0, stream>>>(add_W,   aWh,  65536 / 4);
    cvt16<<<192, 256, 0, stream>>>(read_W, rWh,  196608 / 4);
    cvt16<<<5001, 256, 0, stream>>>(qa_emb, qaEh, 5120256 / 4);
    mkcvt<<<8, 256, 0, stream>>>(Mk, Mkh);
    hipMemsetAsync(bufR2, 0, 4 * sizeof(float), stream);

    for (int c = 0; c < NCH; ++c) {
        const int s0 = c * CS;

        prep128<<<Nc / 8, 256, 0, stream>>>(
            q_data, time_data, attempt_data, hint_data, hintT_data,
            q_emb, time_emb, att_emb, ht_emb, Xp, S3p, QEp, s0, CS, Nc);

        // G1: [T1;T2] = tanh(lin1([X1;X2]))  (in-place Xp, 2Nc rows)
        gemm16<1><<<dim3(2 * Nc / 128, 1), 256, 0, stream>>>(
            Xp, dWh, nullptr, diff_b, nullptr, Xp, nullptr,
            nullptr, nullptr, nullptr, nullptr, nullptr, nullptr, 128, Nc, s0, CS);
        // G2: sig(lin2): rows<Nc -> tf; rows>=Nc -> x3 = qe + df*s3  (in-place)
        gemm16<2><<<dim3(2 * Nc / 128, 1), 256, 0, stream>>>(
            Xp, d2Wh, nullptr, diff2_b, nullptr, Xp, nullptr,
            QEp, S3p, nullptr, nullptr, nullptr, nullptr, 128, Nc, s0, CS);
        // G3: qp = lin1(x3) -> Xp[0:Nc); fused ie = qp + tf*te -> RDIE[:,256:)
        gemm16<3><<<dim3(Nc / 128, 1), 256, 0, stream>>>(
            Xp + (size_t)Nc * 128, dWh, nullptr, diff_b, nullptr, Xp, nullptr,
            nullptr, nullptr, time_data, time_emb, RDIE, nullptr, 128, Nc, s0, CS);
        // w = softmax(qp @ Mk^T) via MFMA
        wsoftmax_mfma<<<Nc / 128, 256, 0, stream>>>(Xp, Mkh, wbuf);
        // G4: e/a gates, gather-A from fp16 qa_emb, packed (e,a) -> EAu
        gemm16<4><<<dim3(Nc / 128, 4), 256, 0, stream>>>(
            qaEh, eWh, aWh, erase_b, add_b, nullptr, nullptr,
            nullptr, nullptr, qa_data, nullptr, (u16*)EAu, nullptr, 256, Nc, s0, CS);
        // scan -> RD fp16 into RDIE[:,0:256)
        scan_kernel<<<NB, DV, 0, stream>>>(wbuf, EAu, Mv0, MvSt, RDIE, CS, c == 0 ? 1 : 0);

        hipMemsetAsync(bufP, 0, (size_t)Nc * sizeof(float), stream);
        // G5: rc = tanh([rd|ie] @ read_W^T + b); pred partials -> bufP
        gemm16<5><<<dim3(Nc / 128, 4), 256, 0, stream>>>(
            RDIE, rWh, nullptr, read_b, nullptr, nullptr, bufP,
            nullptr, nullptr, nullptr, nullptr, nullptr, pred_W, 384, Nc, s0, CS);

        loss_part<<<Nc / 256, 256, 0, stream>>>(bufP, target, pred_b, out, bufR2, s0, CS, Nc);
    }

    loss_fin<<<1, 1, 0, stream>>>(bufR2, out);
}